// Round 1
// baseline (799.402 us; speedup 1.0000x reference)
//
#include <hip/hip_runtime.h>
#include <cstdint>

// T=2048, D=1024, H=16, HS=64, DFF=4096. fp32 in/out, bf16 MFMA internally.

typedef __bf16 bf16;
typedef __bf16 bf16x4 __attribute__((ext_vector_type(4)));
typedef __bf16 bf16x8 __attribute__((ext_vector_type(8)));
typedef float floatx4 __attribute__((ext_vector_type(4)));

// ---------------------------------------------------------------------------
// Tiled transpose + fp32->bf16 cast:  dst[c][r] = (bf16)src[r][c], batched.
// blockDim (32,8); grid (C/32, R/32, batch)
// ---------------------------------------------------------------------------
__global__ __launch_bounds__(256) void transpose_cast_kernel(
    const float* __restrict__ src, bf16* __restrict__ dst,
    int R, int C, long long sBatch, long long dBatch)
{
    __shared__ float tile[32][33];
    const int tx = threadIdx.x, ty = threadIdx.y;
    src += (size_t)blockIdx.z * sBatch;
    dst += (size_t)blockIdx.z * dBatch;
    const int c0 = blockIdx.x * 32, r0 = blockIdx.y * 32;
#pragma unroll
    for (int i = ty; i < 32; i += 8)
        tile[i][tx] = src[(size_t)(r0 + i) * C + c0 + tx];
    __syncthreads();
#pragma unroll
    for (int i = ty; i < 32; i += 8)
        dst[(size_t)(c0 + i) * R + r0 + tx] = (bf16)tile[tx][i];
}

// ---------------------------------------------------------------------------
// K head-transpose: kt[h][j][s] = qkv[s][1024 + h*64 + j]   (bf16)
// blockDim (32,8); grid (2, 64, 16)
// ---------------------------------------------------------------------------
__global__ __launch_bounds__(256) void transpose_k_kernel(
    const bf16* __restrict__ qkv, bf16* __restrict__ kt)
{
    __shared__ bf16 tile[32][33];
    const int tx = threadIdx.x, ty = threadIdx.y;
    const int h = blockIdx.z;
    const int j0 = blockIdx.x * 32, s0 = blockIdx.y * 32;
#pragma unroll
    for (int i = ty; i < 32; i += 8)
        tile[i][tx] = qkv[(size_t)(s0 + i) * 3072 + 1024 + h * 64 + j0 + tx];
    __syncthreads();
#pragma unroll
    for (int i = ty; i < 32; i += 8)
        kt[(size_t)h * 64 * 2048 + (size_t)(j0 + i) * 2048 + s0 + tx] = tile[tx][i];
}

// ---------------------------------------------------------------------------
// Row LayerNorm over D=1024: fp32 in -> bf16 out. One block (256 thr) per row.
// ---------------------------------------------------------------------------
__global__ __launch_bounds__(256) void ln_kernel(
    const float* __restrict__ x, const float* __restrict__ sc,
    const float* __restrict__ bi, bf16* __restrict__ out)
{
    const int row = blockIdx.x;
    const int tid = threadIdx.x;
    const float4 v = ((const float4*)(x + (size_t)row * 1024))[tid];
    float s1 = v.x + v.y + v.z + v.w;
    float s2 = v.x * v.x + v.y * v.y + v.z * v.z + v.w * v.w;
#pragma unroll
    for (int mm = 1; mm < 64; mm <<= 1) {
        s1 += __shfl_xor(s1, mm);
        s2 += __shfl_xor(s2, mm);
    }
    __shared__ float w1[4], w2[4];
    const int wave = tid >> 6, lane = tid & 63;
    if (lane == 0) { w1[wave] = s1; w2[wave] = s2; }
    __syncthreads();
    s1 = w1[0] + w1[1] + w1[2] + w1[3];
    s2 = w2[0] + w2[1] + w2[2] + w2[3];
    const float mu = s1 * (1.f / 1024.f);
    const float var = fmaxf(s2 * (1.f / 1024.f) - mu * mu, 0.f);
    const float rr = rsqrtf(var + 1e-6f);
    const float4 scv = ((const float4*)sc)[tid];
    const float4 biv = ((const float4*)bi)[tid];
    bf16x4 ov;
    ov[0] = (bf16)((v.x - mu) * rr * scv.x + biv.x);
    ov[1] = (bf16)((v.y - mu) * rr * scv.y + biv.y);
    ov[2] = (bf16)((v.z - mu) * rr * scv.z + biv.z);
    ov[3] = (bf16)((v.w - mu) * rr * scv.w + biv.w);
    *(bf16x4*)(out + (size_t)row * 1024 + tid * 4) = ov;
}

// ---------------------------------------------------------------------------
// bf16 MFMA GEMM:  C[M][N] = A[M][K] * Bt[N][K]^T   (Bt stored transposed)
// 128x128 tile / block (256 thr = 4 waves 2x2, each wave 4x4 of 16x16x32).
// MODE 0: outB = (bf16)acc                       (QKV)
// MODE 1: outF = acc + bias[col] + res[row][col] (Oproj -> x1, FF2 -> d_out)
// MODE 2: outB = (bf16)relu(acc + bias[col])     (FF1)
// M==2048 assumed (grid.y=16); N,K multiples of 128/32.
// ---------------------------------------------------------------------------
template <int MODE>
__global__ __launch_bounds__(256) void gemm_kernel(
    const bf16* __restrict__ A, const bf16* __restrict__ Bt,
    int N, int K,
    float* __restrict__ outF, bf16* __restrict__ outB,
    const float* __restrict__ bias, const float* __restrict__ res)
{
    __shared__ __align__(16) bf16 Alds[128][32];
    __shared__ __align__(16) bf16 Blds[128][32];
    const int tid  = threadIdx.x;
    const int lane = tid & 63;
    const int wave = tid >> 6;
    const int wm = (wave >> 1) * 64;
    const int wn = (wave & 1) * 64;
    const int bm = blockIdx.y * 128;
    const int bn = blockIdx.x * 128;
    const int r15  = lane & 15;
    const int quad = lane >> 4;
    const int srow = tid >> 2;
    const int scol = (tid & 3) * 8;

    floatx4 acc[4][4];
#pragma unroll
    for (int i = 0; i < 4; ++i)
#pragma unroll
        for (int j = 0; j < 4; ++j) acc[i][j] = (floatx4)(0.f);

    const bf16* aptr = A + (size_t)(bm + srow) * K + scol;
    const bf16* bptr = Bt + (size_t)(bn + srow) * K + scol;
    const size_t rowJump = (size_t)64 * K;

    for (int k0 = 0; k0 < K; k0 += 32) {
        const uint4 a0 = *(const uint4*)(aptr + k0);
        const uint4 a1 = *(const uint4*)(aptr + rowJump + k0);
        const uint4 b0 = *(const uint4*)(bptr + k0);
        const uint4 b1 = *(const uint4*)(bptr + rowJump + k0);
        __syncthreads();   // prior iteration's fragment reads complete
        *(uint4*)(&Alds[srow][scol])      = a0;
        *(uint4*)(&Alds[srow + 64][scol]) = a1;
        *(uint4*)(&Blds[srow][scol])      = b0;
        *(uint4*)(&Blds[srow + 64][scol]) = b1;
        __syncthreads();

        bf16x8 af[4], bfr[4];
#pragma unroll
        for (int i = 0; i < 4; ++i)
            af[i] = *(const bf16x8*)(&Alds[wm + i * 16 + r15][quad * 8]);
#pragma unroll
        for (int j = 0; j < 4; ++j)
            bfr[j] = *(const bf16x8*)(&Blds[wn + j * 16 + r15][quad * 8]);
#pragma unroll
        for (int i = 0; i < 4; ++i)
#pragma unroll
            for (int j = 0; j < 4; ++j)
                acc[i][j] = __builtin_amdgcn_mfma_f32_16x16x32_bf16(
                    af[i], bfr[j], acc[i][j], 0, 0, 0);
    }

    // C/D layout (verified m89/m91): col = lane&15, row = (lane>>4)*4 + reg
    const int row0 = bm + wm + quad * 4;
    const int col0 = bn + wn + r15;
#pragma unroll
    for (int i = 0; i < 4; ++i) {
#pragma unroll
        for (int reg = 0; reg < 4; ++reg) {
            const int row = row0 + i * 16 + reg;
#pragma unroll
            for (int j = 0; j < 4; ++j) {
                const int col = col0 + j * 16;
                float v = acc[i][j][reg];
                if (MODE == 0) {
                    outB[(size_t)row * N + col] = (bf16)v;
                } else if (MODE == 1) {
                    outF[(size_t)row * N + col] = v + bias[col] + res[(size_t)row * N + col];
                } else {
                    v += bias[col];
                    outB[(size_t)row * N + col] = (bf16)fmaxf(v, 0.f);
                }
            }
        }
    }
}

// ---------------------------------------------------------------------------
// Causal flash attention. 1 wave handles 4 consecutive query rows of 1 head.
// Lane = key column within a 64-wide s-block; online softmax; output dim=lane.
// blockDim 256 (4 waves); grid (T/16, H)
// ---------------------------------------------------------------------------
__global__ __launch_bounds__(256) void attn_kernel(
    const bf16* __restrict__ qkv, const bf16* __restrict__ kt,
    bf16* __restrict__ out)
{
    __shared__ __align__(16) float qT[4][64][4];  // [wave][dim j][row r]
    __shared__ __align__(16) float pT[4][64][4];  // [wave][s i][row r]
    const int h    = blockIdx.y;
    const int wave = threadIdx.x >> 6;
    const int lane = threadIdx.x & 63;
    const int t0   = blockIdx.x * 16 + wave * 4;
    float (*qw)[4] = qT[wave];
    float (*pw)[4] = pT[wave];

    const bf16* kb = kt + (size_t)h * 64 * 2048;           // [64][2048]
    const bf16* qb = qkv + h * 64;                         // col offset
    const bf16* vb = qkv + 2048 + h * 64;

    {   // load q (scaled by 1/sqrt(HS)=0.125), store transposed [j][r]
        float4 q;
        q.x = (float)qb[(size_t)(t0 + 0) * 3072 + lane] * 0.125f;
        q.y = (float)qb[(size_t)(t0 + 1) * 3072 + lane] * 0.125f;
        q.z = (float)qb[(size_t)(t0 + 2) * 3072 + lane] * 0.125f;
        q.w = (float)qb[(size_t)(t0 + 3) * 3072 + lane] * 0.125f;
        *(float4*)qw[lane] = q;
    }
    asm volatile("s_waitcnt lgkmcnt(0)" ::: "memory");

    float m[4], l[4], o[4];
#pragma unroll
    for (int r = 0; r < 4; ++r) { m[r] = -__builtin_inff(); l[r] = 0.f; o[r] = 0.f; }

    const int nblocks = (t0 + 3) / 64 + 1;
    for (int sb = 0; sb < nblocks; ++sb) {
        const int sbase = sb * 64;
        const int s = sbase + lane;
        float sc[4] = {0.f, 0.f, 0.f, 0.f};
#pragma unroll 4
        for (int j = 0; j < 64; ++j) {
            const float kv = (float)kb[(size_t)j * 2048 + s];
            const float4 q4 = *(const float4*)qw[j];
            sc[0] += q4.x * kv; sc[1] += q4.y * kv;
            sc[2] += q4.z * kv; sc[3] += q4.w * kv;
        }
        float p4[4];
#pragma unroll
        for (int r = 0; r < 4; ++r) {
            const float scr = (s <= t0 + r) ? sc[r] : -__builtin_inff();
            float bmx = scr;
#pragma unroll
            for (int mm = 1; mm < 64; mm <<= 1) bmx = fmaxf(bmx, __shfl_xor(bmx, mm));
            const float newm = fmaxf(m[r], bmx);
            const float alpha = __expf(m[r] - newm);   // m=-inf only pre-first-valid
            const float p = __expf(scr - newm);
            float bs = p;
#pragma unroll
            for (int mm = 1; mm < 64; mm <<= 1) bs += __shfl_xor(bs, mm);
            l[r] = l[r] * alpha + bs;
            o[r] *= alpha;
            m[r] = newm;
            p4[r] = p;
        }
        asm volatile("s_waitcnt lgkmcnt(0)" ::: "memory");
        {
            float4 pv; pv.x = p4[0]; pv.y = p4[1]; pv.z = p4[2]; pv.w = p4[3];
            *(float4*)pw[lane] = pv;
        }
        asm volatile("s_waitcnt lgkmcnt(0)" ::: "memory");
#pragma unroll 4
        for (int i = 0; i < 64; ++i) {
            const float vv = (float)vb[(size_t)(sbase + i) * 3072 + lane];
            const float4 pp = *(const float4*)pw[i];   // broadcast read
            o[0] += pp.x * vv; o[1] += pp.y * vv;
            o[2] += pp.z * vv; o[3] += pp.w * vv;
        }
        asm volatile("s_waitcnt lgkmcnt(0)" ::: "memory");
    }
#pragma unroll
    for (int r = 0; r < 4; ++r)
        out[(size_t)(t0 + r) * 1024 + h * 64 + lane] = (bf16)(o[r] / l[r]);
}

// ---------------------------------------------------------------------------
extern "C" void kernel_launch(void* const* d_in, const int* in_sizes, int n_in,
                              void* d_out, int out_size, void* d_ws, size_t ws_size,
                              hipStream_t stream)
{
    const float* x    = (const float*)d_in[0];
    const float* Wq   = (const float*)d_in[1];
    const float* Wk   = (const float*)d_in[2];
    const float* Wv   = (const float*)d_in[3];
    const float* Wo   = (const float*)d_in[4];
    const float* bo   = (const float*)d_in[5];
    const float* W1   = (const float*)d_in[6];
    const float* b1   = (const float*)d_in[7];
    const float* W2   = (const float*)d_in[8];
    const float* b2   = (const float*)d_in[9];
    const float* ln1s = (const float*)d_in[10];
    const float* ln1b = (const float*)d_in[11];
    const float* ln2s = (const float*)d_in[12];
    const float* ln2b = (const float*)d_in[13];

    char* ws = (char*)d_ws;
    // persistent region
    bf16*  W1t  = (bf16*)(ws + 0);          //  8 MB  [4096][1024]
    bf16*  W2t  = (bf16*)(ws + 8388608);    //  8 MB  [1024][4096]
    bf16*  Obuf = (bf16*)(ws + 16777216);   //  4 MB  [2048][1024]
    float* x1   = (float*)(ws + 20971520);  //  8 MB  [2048][1024]
    bf16*  h2   = (bf16*)(ws + 29360128);   //  4 MB  [2048][1024]
    // early region (dead after attention/Oproj) — ff1 aliases its start
    char*  rb    = ws + 33554432;
    bf16*  Wqkvt = (bf16*)(rb + 0);          //  6 MB  [3072][1024]
    bf16*  Wot   = (bf16*)(rb + 6291456);    //  2 MB  [1024][1024]
    bf16*  hbuf  = (bf16*)(rb + 8388608);    //  4 MB  [2048][1024]
    bf16*  QKV   = (bf16*)(rb + 12582912);   // 12 MB  [2048][3072]
    bf16*  Kt    = (bf16*)(rb + 25165824);   //  4 MB  [16][64][2048]
    bf16*  ff1   = (bf16*)(rb + 0);          // 16 MB  [2048][4096] (aliases, safe)

    const dim3 tb(32, 8);
    // weight transpose-casts (B^T layout, bf16)
    transpose_cast_kernel<<<dim3(2, 32, 16), tb, 0, stream>>>(Wq, Wqkvt,              1024, 64,   65536, 65536);
    transpose_cast_kernel<<<dim3(2, 32, 16), tb, 0, stream>>>(Wk, Wqkvt + 1024*1024,  1024, 64,   65536, 65536);
    transpose_cast_kernel<<<dim3(2, 32, 16), tb, 0, stream>>>(Wv, Wqkvt + 2048*1024,  1024, 64,   65536, 65536);
    transpose_cast_kernel<<<dim3(32, 32, 1), tb, 0, stream>>>(Wo, Wot, 1024, 1024, 0, 0);
    transpose_cast_kernel<<<dim3(128, 32, 1), tb, 0, stream>>>(W1, W1t, 1024, 4096, 0, 0);
    transpose_cast_kernel<<<dim3(32, 128, 1), tb, 0, stream>>>(W2, W2t, 4096, 1024, 0, 0);

    ln_kernel<<<2048, 256, 0, stream>>>(x, ln1s, ln1b, hbuf);
    gemm_kernel<0><<<dim3(24, 16), 256, 0, stream>>>(hbuf, Wqkvt, 3072, 1024, nullptr, QKV, nullptr, nullptr);
    transpose_k_kernel<<<dim3(2, 64, 16), tb, 0, stream>>>(QKV, Kt);
    attn_kernel<<<dim3(128, 16), 256, 0, stream>>>(QKV, Kt, Obuf);
    gemm_kernel<1><<<dim3(8, 16), 256, 0, stream>>>(Obuf, Wot, 1024, 1024, x1, nullptr, bo, x);
    ln_kernel<<<2048, 256, 0, stream>>>(x1, ln2s, ln2b, h2);
    gemm_kernel<2><<<dim3(32, 16), 256, 0, stream>>>(h2, W1t, 4096, 1024, nullptr, ff1, b1, nullptr);
    gemm_kernel<1><<<dim3(8, 16), 256, 0, stream>>>(ff1, W2t, 1024, 4096, (float*)d_out, nullptr, b2, x1);
}

// Round 2
// 371.065 us; speedup vs baseline: 2.1543x; 2.1543x over previous
//
#include <hip/hip_runtime.h>
#include <cstdint>

// T=2048, D=1024, H=16, HS=64, DFF=4096. fp32 in/out, bf16 MFMA internally.

typedef __bf16 bf16;
typedef __bf16 bf16x4 __attribute__((ext_vector_type(4)));
typedef __bf16 bf16x8 __attribute__((ext_vector_type(8)));
typedef float floatx4 __attribute__((ext_vector_type(4)));

// ---------------------------------------------------------------------------
// Tiled transpose + fp32->bf16 cast:  dst[c][r] = (bf16)src[r][c], batched.
// blockDim (32,8); grid (C/32, R/32, batch)
// ---------------------------------------------------------------------------
__global__ __launch_bounds__(256) void transpose_cast_kernel(
    const float* __restrict__ src, bf16* __restrict__ dst,
    int R, int C, long long sBatch, long long dBatch)
{
    __shared__ float tile[32][33];
    const int tx = threadIdx.x, ty = threadIdx.y;
    src += (size_t)blockIdx.z * sBatch;
    dst += (size_t)blockIdx.z * dBatch;
    const int c0 = blockIdx.x * 32, r0 = blockIdx.y * 32;
#pragma unroll
    for (int i = ty; i < 32; i += 8)
        tile[i][tx] = src[(size_t)(r0 + i) * C + c0 + tx];
    __syncthreads();
#pragma unroll
    for (int i = ty; i < 32; i += 8)
        dst[(size_t)(c0 + i) * R + r0 + tx] = (bf16)tile[tx][i];
}

// ---------------------------------------------------------------------------
// Head-transpose from QKV: dst[h][j][s] = qkv[s][colOff + h*64 + j]   (bf16)
// blockDim (32,8); grid (2, 64, 16).  colOff=2048 -> V section.
// ---------------------------------------------------------------------------
__global__ __launch_bounds__(256) void transpose_head_kernel(
    const bf16* __restrict__ qkv, bf16* __restrict__ dst, int colOff)
{
    __shared__ bf16 tile[32][33];
    const int tx = threadIdx.x, ty = threadIdx.y;
    const int h = blockIdx.z;
    const int j0 = blockIdx.x * 32, s0 = blockIdx.y * 32;
#pragma unroll
    for (int i = ty; i < 32; i += 8)
        tile[i][tx] = qkv[(size_t)(s0 + i) * 3072 + colOff + h * 64 + j0 + tx];
    __syncthreads();
#pragma unroll
    for (int i = ty; i < 32; i += 8)
        dst[(size_t)h * 64 * 2048 + (size_t)(j0 + i) * 2048 + s0 + tx] = tile[tx][i];
}

// ---------------------------------------------------------------------------
// Row LayerNorm over D=1024: fp32 in -> bf16 out. One block (256 thr) per row.
// ---------------------------------------------------------------------------
__global__ __launch_bounds__(256) void ln_kernel(
    const float* __restrict__ x, const float* __restrict__ sc,
    const float* __restrict__ bi, bf16* __restrict__ out)
{
    const int row = blockIdx.x;
    const int tid = threadIdx.x;
    const float4 v = ((const float4*)(x + (size_t)row * 1024))[tid];
    float s1 = v.x + v.y + v.z + v.w;
    float s2 = v.x * v.x + v.y * v.y + v.z * v.z + v.w * v.w;
#pragma unroll
    for (int mm = 1; mm < 64; mm <<= 1) {
        s1 += __shfl_xor(s1, mm);
        s2 += __shfl_xor(s2, mm);
    }
    __shared__ float w1[4], w2[4];
    const int wave = tid >> 6, lane = tid & 63;
    if (lane == 0) { w1[wave] = s1; w2[wave] = s2; }
    __syncthreads();
    s1 = w1[0] + w1[1] + w1[2] + w1[3];
    s2 = w2[0] + w2[1] + w2[2] + w2[3];
    const float mu = s1 * (1.f / 1024.f);
    const float var = fmaxf(s2 * (1.f / 1024.f) - mu * mu, 0.f);
    const float rr = rsqrtf(var + 1e-6f);
    const float4 scv = ((const float4*)sc)[tid];
    const float4 biv = ((const float4*)bi)[tid];
    bf16x4 ov;
    ov[0] = (bf16)((v.x - mu) * rr * scv.x + biv.x);
    ov[1] = (bf16)((v.y - mu) * rr * scv.y + biv.y);
    ov[2] = (bf16)((v.z - mu) * rr * scv.z + biv.z);
    ov[3] = (bf16)((v.w - mu) * rr * scv.w + biv.w);
    *(bf16x4*)(out + (size_t)row * 1024 + tid * 4) = ov;
}

// ---------------------------------------------------------------------------
// bf16 MFMA GEMM:  C[M][N] = A[M][K] * Bt[N][K]^T   (Bt stored transposed)
// 128x128 tile / block (256 thr = 4 waves 2x2, each wave 4x4 of 16x16x32).
// MODE 0: outB = (bf16)acc                       (QKV)
// MODE 1: outF = acc + bias[col] + res[row][col] (Oproj -> x1, FF2 -> d_out)
// MODE 2: outB = (bf16)relu(acc + bias[col])     (FF1)
// ---------------------------------------------------------------------------
template <int MODE>
__global__ __launch_bounds__(256) void gemm_kernel(
    const bf16* __restrict__ A, const bf16* __restrict__ Bt,
    int N, int K,
    float* __restrict__ outF, bf16* __restrict__ outB,
    const float* __restrict__ bias, const float* __restrict__ res)
{
    __shared__ __align__(16) bf16 Alds[128][32];
    __shared__ __align__(16) bf16 Blds[128][32];
    const int tid  = threadIdx.x;
    const int lane = tid & 63;
    const int wave = tid >> 6;
    const int wm = (wave >> 1) * 64;
    const int wn = (wave & 1) * 64;
    const int bm = blockIdx.y * 128;
    const int bn = blockIdx.x * 128;
    const int r15  = lane & 15;
    const int quad = lane >> 4;
    const int srow = tid >> 2;
    const int scol = (tid & 3) * 8;

    floatx4 acc[4][4];
#pragma unroll
    for (int i = 0; i < 4; ++i)
#pragma unroll
        for (int j = 0; j < 4; ++j) acc[i][j] = (floatx4)(0.f);

    const bf16* aptr = A + (size_t)(bm + srow) * K + scol;
    const bf16* bptr = Bt + (size_t)(bn + srow) * K + scol;
    const size_t rowJump = (size_t)64 * K;

    for (int k0 = 0; k0 < K; k0 += 32) {
        const uint4 a0 = *(const uint4*)(aptr + k0);
        const uint4 a1 = *(const uint4*)(aptr + rowJump + k0);
        const uint4 b0 = *(const uint4*)(bptr + k0);
        const uint4 b1 = *(const uint4*)(bptr + rowJump + k0);
        __syncthreads();   // prior iteration's fragment reads complete
        *(uint4*)(&Alds[srow][scol])      = a0;
        *(uint4*)(&Alds[srow + 64][scol]) = a1;
        *(uint4*)(&Blds[srow][scol])      = b0;
        *(uint4*)(&Blds[srow + 64][scol]) = b1;
        __syncthreads();

        bf16x8 af[4], bfr[4];
#pragma unroll
        for (int i = 0; i < 4; ++i)
            af[i] = *(const bf16x8*)(&Alds[wm + i * 16 + r15][quad * 8]);
#pragma unroll
        for (int j = 0; j < 4; ++j)
            bfr[j] = *(const bf16x8*)(&Blds[wn + j * 16 + r15][quad * 8]);
#pragma unroll
        for (int i = 0; i < 4; ++i)
#pragma unroll
            for (int j = 0; j < 4; ++j)
                acc[i][j] = __builtin_amdgcn_mfma_f32_16x16x32_bf16(
                    af[i], bfr[j], acc[i][j], 0, 0, 0);
    }

    // C/D layout (verified m89/m91): col = lane&15, row = (lane>>4)*4 + reg
    const int row0 = bm + wm + quad * 4;
    const int col0 = bn + wn + r15;
#pragma unroll
    for (int i = 0; i < 4; ++i) {
#pragma unroll
        for (int reg = 0; reg < 4; ++reg) {
            const int row = row0 + i * 16 + reg;
#pragma unroll
            for (int j = 0; j < 4; ++j) {
                const int col = col0 + j * 16;
                float v = acc[i][j][reg];
                if (MODE == 0) {
                    outB[(size_t)row * N + col] = (bf16)v;
                } else if (MODE == 1) {
                    outF[(size_t)row * N + col] = v + bias[col] + res[(size_t)row * N + col];
                } else {
                    v += bias[col];
                    outB[(size_t)row * N + col] = (bf16)fmaxf(v, 0.f);
                }
            }
        }
    }
}

// ---------------------------------------------------------------------------
// MFMA flash attention (causal). Block = 4 waves; each block processes the
// balanced q-tile pair {i, 31-i} (33 key-tile steps exactly). Per q-tile of
// 64 rows: wave w owns rows w*16..w*16+15. K-tiles of 64 keys.
// Q,K staged [s][d] (A / B^T operands directly); V staged pre-transposed
// Vt[h][d][s]. P converts C-layout -> A-layout via LDS (m120 pattern).
// grid (16, H); block 256.
// ---------------------------------------------------------------------------
__global__ __launch_bounds__(256) void attn_kernel(
    const bf16* __restrict__ qkv, const bf16* __restrict__ vt,
    bf16* __restrict__ out)
{
    __shared__ __align__(16) bf16 Qs[64][72];
    __shared__ __align__(16) bf16 Ks[64][72];
    __shared__ __align__(16) bf16 Vs[64][72];      // Vt tile: [dim][key]
    __shared__ __align__(16) bf16 Ps[4][16][72];   // per-wave P tile

    const int h    = blockIdx.y;
    const int tid  = threadIdx.x;
    const int w    = tid >> 6;
    const int lane = tid & 63;
    const int r15  = lane & 15;
    const int quad = lane >> 4;
    const int sr   = tid >> 2;         // staging row 0..63
    const int sc   = (tid & 3) * 16;   // staging col {0,16,32,48}

    const bf16* qsec = qkv + h * 64;
    const bf16* ksec = qkv + 1024 + h * 64;
    const bf16* vth  = vt + (size_t)h * 64 * 2048;

#pragma unroll 1
    for (int half = 0; half < 2; ++half) {
        const int qt    = (half == 0) ? (int)blockIdx.x : 31 - (int)blockIdx.x;
        const int qrow0 = qt * 64;

        {   // stage Q tile
            const bf16* g = qsec + (size_t)(qrow0 + sr) * 3072 + sc;
            const uint4 q0 = *(const uint4*)g;
            const uint4 q1 = *(const uint4*)(g + 8);
            __syncthreads();
            *(uint4*)&Qs[sr][sc]     = q0;
            *(uint4*)&Qs[sr][sc + 8] = q1;
            __syncthreads();
        }
        bf16x8 qf[2];
        qf[0] = *(const bf16x8*)&Qs[w * 16 + r15][quad * 8];
        qf[1] = *(const bf16x8*)&Qs[w * 16 + r15][32 + quad * 8];

        float m[4], l[4];
        floatx4 O[4];
#pragma unroll
        for (int r = 0; r < 4; ++r) { m[r] = -3.0e38f; l[r] = 0.f; }
#pragma unroll
        for (int j = 0; j < 4; ++j) O[j] = (floatx4)(0.f);

#pragma unroll 1
        for (int sb = 0; sb <= qt; ++sb) {
            const int s0 = sb * 64;
            const bf16* gk = ksec + (size_t)(s0 + sr) * 3072 + sc;
            const uint4 k0v = *(const uint4*)gk;
            const uint4 k1v = *(const uint4*)(gk + 8);
            const bf16* gv = vth + (size_t)sr * 2048 + s0 + sc;
            const uint4 v0v = *(const uint4*)gv;
            const uint4 v1v = *(const uint4*)(gv + 8);
            __syncthreads();           // prior step's K/V fragment reads done
            *(uint4*)&Ks[sr][sc]     = k0v;
            *(uint4*)&Ks[sr][sc + 8] = k1v;
            *(uint4*)&Vs[sr][sc]     = v0v;
            *(uint4*)&Vs[sr][sc + 8] = v1v;
            __syncthreads();

            // S = Q K^T  (wave's 16 rows x 64 keys)
            floatx4 S[4];
#pragma unroll
            for (int j = 0; j < 4; ++j) S[j] = (floatx4)(0.f);
#pragma unroll
            for (int c = 0; c < 2; ++c) {
#pragma unroll
                for (int j = 0; j < 4; ++j) {
                    const bf16x8 b = *(const bf16x8*)&Ks[j * 16 + r15][c * 32 + quad * 8];
                    S[j] = __builtin_amdgcn_mfma_f32_16x16x32_bf16(qf[c], b, S[j], 0, 0, 0);
                }
            }
#pragma unroll
            for (int j = 0; j < 4; ++j) {
#pragma unroll
                for (int r = 0; r < 4; ++r) S[j][r] *= 0.125f;
            }
            if (sb == qt) {   // diagonal tile: mask col > row (within 64x64 tile)
                const int rl = w * 16 + quad * 4;
#pragma unroll
                for (int j = 0; j < 4; ++j) {
                    const int col = j * 16 + r15;
#pragma unroll
                    for (int r = 0; r < 4; ++r)
                        if (col > rl + r) S[j][r] = -3.0e38f;
                }
            }
            // online softmax (row stats live in 16-lane groups)
#pragma unroll
            for (int r = 0; r < 4; ++r) {
                float mx = fmaxf(fmaxf(S[0][r], S[1][r]), fmaxf(S[2][r], S[3][r]));
#pragma unroll
                for (int d = 1; d < 16; d <<= 1) mx = fmaxf(mx, __shfl_xor(mx, d));
                const float nm = fmaxf(m[r], mx);
                const float al = __expf(m[r] - nm);
                float sum = 0.f;
#pragma unroll
                for (int j = 0; j < 4; ++j) {
                    const float p = __expf(S[j][r] - nm);
                    S[j][r] = p;
                    sum += p;
                }
#pragma unroll
                for (int d = 1; d < 16; d <<= 1) sum += __shfl_xor(sum, d);
                l[r] = l[r] * al + sum;
                m[r] = nm;
#pragma unroll
                for (int j = 0; j < 4; ++j) O[j][r] *= al;
            }
            // P: C-layout -> A-layout via LDS (per-wave region, no barrier)
#pragma unroll
            for (int r = 0; r < 4; ++r)
#pragma unroll
                for (int j = 0; j < 4; ++j)
                    Ps[w][quad * 4 + r][j * 16 + r15] = (bf16)S[j][r];
            // O += P V   (A from Ps, B^T from Vs)
#pragma unroll
            for (int c = 0; c < 2; ++c) {
                const bf16x8 a = *(const bf16x8*)&Ps[w][r15][c * 32 + quad * 8];
#pragma unroll
                for (int j = 0; j < 4; ++j) {
                    const bf16x8 b = *(const bf16x8*)&Vs[j * 16 + r15][c * 32 + quad * 8];
                    O[j] = __builtin_amdgcn_mfma_f32_16x16x32_bf16(a, b, O[j], 0, 0, 0);
                }
            }
        }
        // epilogue: out[q][h*64+dim] = O / l
#pragma unroll
        for (int r = 0; r < 4; ++r) {
            const float inv = 1.0f / l[r];
            const int row = qrow0 + w * 16 + quad * 4 + r;
#pragma unroll
            for (int j = 0; j < 4; ++j)
                out[(size_t)row * 1024 + h * 64 + j * 16 + r15] = (bf16)(O[j][r] * inv);
        }
    }
}

// ---------------------------------------------------------------------------
extern "C" void kernel_launch(void* const* d_in, const int* in_sizes, int n_in,
                              void* d_out, int out_size, void* d_ws, size_t ws_size,
                              hipStream_t stream)
{
    const float* x    = (const float*)d_in[0];
    const float* Wq   = (const float*)d_in[1];
    const float* Wk   = (const float*)d_in[2];
    const float* Wv   = (const float*)d_in[3];
    const float* Wo   = (const float*)d_in[4];
    const float* bo   = (const float*)d_in[5];
    const float* W1   = (const float*)d_in[6];
    const float* b1   = (const float*)d_in[7];
    const float* W2   = (const float*)d_in[8];
    const float* b2   = (const float*)d_in[9];
    const float* ln1s = (const float*)d_in[10];
    const float* ln1b = (const float*)d_in[11];
    const float* ln2s = (const float*)d_in[12];
    const float* ln2b = (const float*)d_in[13];

    char* ws = (char*)d_ws;
    // persistent region
    bf16*  W1t  = (bf16*)(ws + 0);          //  8 MB  [4096][1024]
    bf16*  W2t  = (bf16*)(ws + 8388608);    //  8 MB  [1024][4096]
    bf16*  Obuf = (bf16*)(ws + 16777216);   //  4 MB  [2048][1024]
    float* x1   = (float*)(ws + 20971520);  //  8 MB  [2048][1024]
    bf16*  h2   = (bf16*)(ws + 29360128);   //  4 MB  [2048][1024]
    // early region (dead after attention/Oproj) — ff1 aliases its start
    char*  rb    = ws + 33554432;
    bf16*  Wqkvt = (bf16*)(rb + 0);          //  6 MB  [3072][1024]
    bf16*  Wot   = (bf16*)(rb + 6291456);    //  2 MB  [1024][1024]
    bf16*  hbuf  = (bf16*)(rb + 8388608);    //  4 MB  [2048][1024]
    bf16*  QKV   = (bf16*)(rb + 12582912);   // 12 MB  [2048][3072]
    bf16*  Vt    = (bf16*)(rb + 25165824);   //  4 MB  [16][64][2048]
    bf16*  ff1   = (bf16*)(rb + 0);          // 16 MB  [2048][4096] (aliases, safe)

    const dim3 tb(32, 8);
    // weight transpose-casts (B^T layout, bf16)
    transpose_cast_kernel<<<dim3(2, 32, 16), tb, 0, stream>>>(Wq, Wqkvt,              1024, 64,   65536, 65536);
    transpose_cast_kernel<<<dim3(2, 32, 16), tb, 0, stream>>>(Wk, Wqkvt + 1024*1024,  1024, 64,   65536, 65536);
    transpose_cast_kernel<<<dim3(2, 32, 16), tb, 0, stream>>>(Wv, Wqkvt + 2048*1024,  1024, 64,   65536, 65536);
    transpose_cast_kernel<<<dim3(32, 32, 1), tb, 0, stream>>>(Wo, Wot, 1024, 1024, 0, 0);
    transpose_cast_kernel<<<dim3(128, 32, 1), tb, 0, stream>>>(W1, W1t, 1024, 4096, 0, 0);
    transpose_cast_kernel<<<dim3(32, 128, 1), tb, 0, stream>>>(W2, W2t, 4096, 1024, 0, 0);

    ln_kernel<<<2048, 256, 0, stream>>>(x, ln1s, ln1b, hbuf);
    gemm_kernel<0><<<dim3(24, 16), 256, 0, stream>>>(hbuf, Wqkvt, 3072, 1024, nullptr, QKV, nullptr, nullptr);
    transpose_head_kernel<<<dim3(2, 64, 16), tb, 0, stream>>>(QKV, Vt, 2048);
    attn_kernel<<<dim3(16, 16), 256, 0, stream>>>(QKV, Vt, Obuf);
    gemm_kernel<1><<<dim3(8, 16), 256, 0, stream>>>(Obuf, Wot, 1024, 1024, x1, nullptr, bo, x);
    ln_kernel<<<2048, 256, 0, stream>>>(x1, ln2s, ln2b, h2);
    gemm_kernel<2><<<dim3(32, 16), 256, 0, stream>>>(h2, W1t, 4096, 1024, nullptr, ff1, b1, nullptr);
    gemm_kernel<1><<<dim3(8, 16), 256, 0, stream>>>(ff1, W2t, 1024, 4096, (float*)d_out, nullptr, b2, x1);
}

// Round 3
// 350.496 us; speedup vs baseline: 2.2808x; 1.0587x over previous
//
#include <hip/hip_runtime.h>
#include <cstdint>

// T=2048, D=1024, H=16, HS=64, DFF=4096. fp32 in/out, bf16 MFMA internally.

typedef __bf16 bf16;
typedef __bf16 bf16x4 __attribute__((ext_vector_type(4)));
typedef __bf16 bf16x8 __attribute__((ext_vector_type(8)));
typedef float floatx4 __attribute__((ext_vector_type(4)));

// async global->LDS 16B/lane. LDS dest is wave-uniform base + lane*16 (HW rule).
__device__ __forceinline__ void ld_g2l(const bf16* g, bf16* l) {
    __builtin_amdgcn_global_load_lds(
        (const __attribute__((address_space(1))) void*)g,
        (__attribute__((address_space(3))) void*)l, 16, 0, 0);
}

// ---------------------------------------------------------------------------
// Tiled transpose + fp32->bf16 cast:  dst[c][r] = (bf16)src[r][c], batched.
// blockDim (32,8); grid (C/32, R/32, batch)
// ---------------------------------------------------------------------------
__global__ __launch_bounds__(256) void transpose_cast_kernel(
    const float* __restrict__ src, bf16* __restrict__ dst,
    int R, int C, long long sBatch, long long dBatch)
{
    __shared__ float tile[32][33];
    const int tx = threadIdx.x, ty = threadIdx.y;
    src += (size_t)blockIdx.z * sBatch;
    dst += (size_t)blockIdx.z * dBatch;
    const int c0 = blockIdx.x * 32, r0 = blockIdx.y * 32;
#pragma unroll
    for (int i = ty; i < 32; i += 8)
        tile[i][tx] = src[(size_t)(r0 + i) * C + c0 + tx];
    __syncthreads();
#pragma unroll
    for (int i = ty; i < 32; i += 8)
        dst[(size_t)(c0 + i) * R + r0 + tx] = (bf16)tile[tx][i];
}

// ---------------------------------------------------------------------------
// Head-transpose from QKV: dst[h][j][s] = qkv[s][colOff + h*64 + j]   (bf16)
// blockDim (32,8); grid (2, 64, 16).  colOff=2048 -> V section.
// ---------------------------------------------------------------------------
__global__ __launch_bounds__(256) void transpose_head_kernel(
    const bf16* __restrict__ qkv, bf16* __restrict__ dst, int colOff)
{
    __shared__ bf16 tile[32][33];
    const int tx = threadIdx.x, ty = threadIdx.y;
    const int h = blockIdx.z;
    const int j0 = blockIdx.x * 32, s0 = blockIdx.y * 32;
#pragma unroll
    for (int i = ty; i < 32; i += 8)
        tile[i][tx] = qkv[(size_t)(s0 + i) * 3072 + colOff + h * 64 + j0 + tx];
    __syncthreads();
#pragma unroll
    for (int i = ty; i < 32; i += 8)
        dst[(size_t)h * 64 * 2048 + (size_t)(j0 + i) * 2048 + s0 + tx] = tile[tx][i];
}

// ---------------------------------------------------------------------------
// Row LayerNorm over D=1024: fp32 in -> bf16 out. One block (256 thr) per row.
// ---------------------------------------------------------------------------
__global__ __launch_bounds__(256) void ln_kernel(
    const float* __restrict__ x, const float* __restrict__ sc,
    const float* __restrict__ bi, bf16* __restrict__ out)
{
    const int row = blockIdx.x;
    const int tid = threadIdx.x;
    const float4 v = ((const float4*)(x + (size_t)row * 1024))[tid];
    float s1 = v.x + v.y + v.z + v.w;
    float s2 = v.x * v.x + v.y * v.y + v.z * v.z + v.w * v.w;
#pragma unroll
    for (int mm = 1; mm < 64; mm <<= 1) {
        s1 += __shfl_xor(s1, mm);
        s2 += __shfl_xor(s2, mm);
    }
    __shared__ float w1[4], w2[4];
    const int wave = tid >> 6, lane = tid & 63;
    if (lane == 0) { w1[wave] = s1; w2[wave] = s2; }
    __syncthreads();
    s1 = w1[0] + w1[1] + w1[2] + w1[3];
    s2 = w2[0] + w2[1] + w2[2] + w2[3];
    const float mu = s1 * (1.f / 1024.f);
    const float var = fmaxf(s2 * (1.f / 1024.f) - mu * mu, 0.f);
    const float rr = rsqrtf(var + 1e-6f);
    const float4 scv = ((const float4*)sc)[tid];
    const float4 biv = ((const float4*)bi)[tid];
    bf16x4 ov;
    ov[0] = (bf16)((v.x - mu) * rr * scv.x + biv.x);
    ov[1] = (bf16)((v.y - mu) * rr * scv.y + biv.y);
    ov[2] = (bf16)((v.z - mu) * rr * scv.z + biv.z);
    ov[3] = (bf16)((v.w - mu) * rr * scv.w + biv.w);
    *(bf16x4*)(out + (size_t)row * 1024 + tid * 4) = ov;
}

// ---------------------------------------------------------------------------
// bf16 MFMA GEMM:  C[M][N] = A[M][K] * Bt[N][K]^T   (Bt stored transposed)
// Block = 256 thr = 4 waves arranged (4/WGX)xWGX; wave tile = MI*16 x MJ*16;
// block tile = BM x BN. Staging via global_load_lds width=16 (m97 pattern).
// MODE 0: outB = (bf16)acc                       (QKV)
// MODE 1: outF = acc + bias[col] + res[row][col] (Oproj -> x1, FF2 -> d_out)
// MODE 2: outB = (bf16)relu(acc + bias[col])     (FF1)
// ---------------------------------------------------------------------------
template <int MODE, int BM, int BN, int MI, int MJ, int WGX>
__global__ __launch_bounds__(256) void gemm_kernel(
    const bf16* __restrict__ A, const bf16* __restrict__ Bt,
    int N, int K,
    float* __restrict__ outF, bf16* __restrict__ outB,
    const float* __restrict__ bias, const float* __restrict__ res)
{
    __shared__ __align__(16) bf16 Alds[BM][32];
    __shared__ __align__(16) bf16 Blds[BN][32];
    const int tid  = threadIdx.x;
    const int lane = tid & 63;
    const int w    = tid >> 6;
    const int wm = (w / WGX) * (MI * 16);
    const int wn = (w % WGX) * (MJ * 16);
    const int bm = blockIdx.y * BM;
    const int bn = blockIdx.x * BN;
    const int r15  = lane & 15;
    const int quad = lane >> 4;
    const int srow = tid >> 2;        // 0..63
    const int scol = (tid & 3) * 8;   // element offset {0,8,16,24}

    floatx4 acc[MI][MJ];
#pragma unroll
    for (int i = 0; i < MI; ++i)
#pragma unroll
        for (int j = 0; j < MJ; ++j) acc[i][j] = (floatx4)(0.f);

    const bf16* aptr = A + (size_t)(bm + srow) * K + scol;
    const bf16* bptr = Bt + (size_t)(bn + srow) * K + scol;
    // wave-uniform LDS bases: lane l lands at base + l*16B (= row w*16 + l>>2,
    // col (l&3)*8) -- matches the [64][32] bf16 row layout exactly.
    bf16* aldsW = &Alds[w * 16][0];
    bf16* bldsW = &Blds[w * 16][0];

    for (int k0 = 0; k0 < K; k0 += 32) {
        __syncthreads();   // prior iteration's fragment reads complete
#pragma unroll
        for (int rr = 0; rr < BM / 64; ++rr)
            ld_g2l(aptr + (size_t)rr * 64 * K + k0, aldsW + rr * 64 * 32);
#pragma unroll
        for (int rr = 0; rr < BN / 64; ++rr)
            ld_g2l(bptr + (size_t)rr * 64 * K + k0, bldsW + rr * 64 * 32);
        __syncthreads();   // staging complete (vmcnt drained by barrier)

        bf16x8 af[MI], bfr[MJ];
#pragma unroll
        for (int i = 0; i < MI; ++i)
            af[i] = *(const bf16x8*)(&Alds[wm + i * 16 + r15][quad * 8]);
#pragma unroll
        for (int j = 0; j < MJ; ++j)
            bfr[j] = *(const bf16x8*)(&Blds[wn + j * 16 + r15][quad * 8]);
#pragma unroll
        for (int i = 0; i < MI; ++i)
#pragma unroll
            for (int j = 0; j < MJ; ++j)
                acc[i][j] = __builtin_amdgcn_mfma_f32_16x16x32_bf16(
                    af[i], bfr[j], acc[i][j], 0, 0, 0);
    }

    // C/D layout (verified m89/m91): col = lane&15, row = (lane>>4)*4 + reg
    const int row0 = bm + wm + quad * 4;
    const int col0 = bn + wn + r15;
#pragma unroll
    for (int i = 0; i < MI; ++i) {
#pragma unroll
        for (int reg = 0; reg < 4; ++reg) {
            const int row = row0 + i * 16 + reg;
#pragma unroll
            for (int j = 0; j < MJ; ++j) {
                const int col = col0 + j * 16;
                float v = acc[i][j][reg];
                if (MODE == 0) {
                    outB[(size_t)row * N + col] = (bf16)v;
                } else if (MODE == 1) {
                    outF[(size_t)row * N + col] = v + bias[col] + res[(size_t)row * N + col];
                } else {
                    v += bias[col];
                    outB[(size_t)row * N + col] = (bf16)fmaxf(v, 0.f);
                }
            }
        }
    }
}

// ---------------------------------------------------------------------------
// MFMA flash attention (causal). Block = 4 waves; each block processes the
// balanced q-tile pair {i, 31-i} (33 key-tile steps exactly). Per q-tile of
// 64 rows: wave w owns rows w*16..w*16+15. K-tiles of 64 keys.
// Q,K staged [s][d] (A / B^T operands directly); V staged pre-transposed
// Vt[h][d][s]. P converts C-layout -> A-layout via LDS (m120 pattern).
// grid (16, H); block 256.
// ---------------------------------------------------------------------------
__global__ __launch_bounds__(256) void attn_kernel(
    const bf16* __restrict__ qkv, const bf16* __restrict__ vt,
    bf16* __restrict__ out)
{
    __shared__ __align__(16) bf16 Qs[64][72];
    __shared__ __align__(16) bf16 Ks[64][72];
    __shared__ __align__(16) bf16 Vs[64][72];      // Vt tile: [dim][key]
    __shared__ __align__(16) bf16 Ps[4][16][72];   // per-wave P tile

    const int h    = blockIdx.y;
    const int tid  = threadIdx.x;
    const int w    = tid >> 6;
    const int lane = tid & 63;
    const int r15  = lane & 15;
    const int quad = lane >> 4;
    const int sr   = tid >> 2;         // staging row 0..63
    const int sc   = (tid & 3) * 16;   // staging col {0,16,32,48}

    const bf16* qsec = qkv + h * 64;
    const bf16* ksec = qkv + 1024 + h * 64;
    const bf16* vth  = vt + (size_t)h * 64 * 2048;

#pragma unroll 1
    for (int half = 0; half < 2; ++half) {
        const int qt    = (half == 0) ? (int)blockIdx.x : 31 - (int)blockIdx.x;
        const int qrow0 = qt * 64;

        {   // stage Q tile
            const bf16* g = qsec + (size_t)(qrow0 + sr) * 3072 + sc;
            const uint4 q0 = *(const uint4*)g;
            const uint4 q1 = *(const uint4*)(g + 8);
            __syncthreads();
            *(uint4*)&Qs[sr][sc]     = q0;
            *(uint4*)&Qs[sr][sc + 8] = q1;
            __syncthreads();
        }
        bf16x8 qf[2];
        qf[0] = *(const bf16x8*)&Qs[w * 16 + r15][quad * 8];
        qf[1] = *(const bf16x8*)&Qs[w * 16 + r15][32 + quad * 8];

        float m[4], l[4];
        floatx4 O[4];
#pragma unroll
        for (int r = 0; r < 4; ++r) { m[r] = -3.0e38f; l[r] = 0.f; }
#pragma unroll
        for (int j = 0; j < 4; ++j) O[j] = (floatx4)(0.f);

#pragma unroll 1
        for (int sb = 0; sb <= qt; ++sb) {
            const int s0 = sb * 64;
            const bf16* gk = ksec + (size_t)(s0 + sr) * 3072 + sc;
            const uint4 k0v = *(const uint4*)gk;
            const uint4 k1v = *(const uint4*)(gk + 8);
            const bf16* gv = vth + (size_t)sr * 2048 + s0 + sc;
            const uint4 v0v = *(const uint4*)gv;
            const uint4 v1v = *(const uint4*)(gv + 8);
            __syncthreads();           // prior step's K/V fragment reads done
            *(uint4*)&Ks[sr][sc]     = k0v;
            *(uint4*)&Ks[sr][sc + 8] = k1v;
            *(uint4*)&Vs[sr][sc]     = v0v;
            *(uint4*)&Vs[sr][sc + 8] = v1v;
            __syncthreads();

            // S = Q K^T  (wave's 16 rows x 64 keys)
            floatx4 S[4];
#pragma unroll
            for (int j = 0; j < 4; ++j) S[j] = (floatx4)(0.f);
#pragma unroll
            for (int c = 0; c < 2; ++c) {
#pragma unroll
                for (int j = 0; j < 4; ++j) {
                    const bf16x8 b = *(const bf16x8*)&Ks[j * 16 + r15][c * 32 + quad * 8];
                    S[j] = __builtin_amdgcn_mfma_f32_16x16x32_bf16(qf[c], b, S[j], 0, 0, 0);
                }
            }
#pragma unroll
            for (int j = 0; j < 4; ++j) {
#pragma unroll
                for (int r = 0; r < 4; ++r) S[j][r] *= 0.125f;
            }
            if (sb == qt) {   // diagonal tile: mask col > row (within 64x64 tile)
                const int rl = w * 16 + quad * 4;
#pragma unroll
                for (int j = 0; j < 4; ++j) {
                    const int col = j * 16 + r15;
#pragma unroll
                    for (int r = 0; r < 4; ++r)
                        if (col > rl + r) S[j][r] = -3.0e38f;
                }
            }
            // online softmax (row stats live in 16-lane groups)
#pragma unroll
            for (int r = 0; r < 4; ++r) {
                float mx = fmaxf(fmaxf(S[0][r], S[1][r]), fmaxf(S[2][r], S[3][r]));
#pragma unroll
                for (int d = 1; d < 16; d <<= 1) mx = fmaxf(mx, __shfl_xor(mx, d));
                const float nm = fmaxf(m[r], mx);
                const float al = __expf(m[r] - nm);
                float sum = 0.f;
#pragma unroll
                for (int j = 0; j < 4; ++j) {
                    const float p = __expf(S[j][r] - nm);
                    S[j][r] = p;
                    sum += p;
                }
#pragma unroll
                for (int d = 1; d < 16; d <<= 1) sum += __shfl_xor(sum, d);
                l[r] = l[r] * al + sum;
                m[r] = nm;
#pragma unroll
                for (int j = 0; j < 4; ++j) O[j][r] *= al;
            }
            // P: C-layout -> A-layout via LDS (per-wave region, no barrier)
#pragma unroll
            for (int r = 0; r < 4; ++r)
#pragma unroll
                for (int j = 0; j < 4; ++j)
                    Ps[w][quad * 4 + r][j * 16 + r15] = (bf16)S[j][r];
            // O += P V   (A from Ps, B^T from Vs)
#pragma unroll
            for (int c = 0; c < 2; ++c) {
                const bf16x8 a = *(const bf16x8*)&Ps[w][r15][c * 32 + quad * 8];
#pragma unroll
                for (int j = 0; j < 4; ++j) {
                    const bf16x8 b = *(const bf16x8*)&Vs[j * 16 + r15][c * 32 + quad * 8];
                    O[j] = __builtin_amdgcn_mfma_f32_16x16x32_bf16(a, b, O[j], 0, 0, 0);
                }
            }
        }
        // epilogue: out[q][h*64+dim] = O / l
#pragma unroll
        for (int r = 0; r < 4; ++r) {
            const float inv = 1.0f / l[r];
            const int row = qrow0 + w * 16 + quad * 4 + r;
#pragma unroll
            for (int j = 0; j < 4; ++j)
                out[(size_t)row * 1024 + h * 64 + j * 16 + r15] = (bf16)(O[j][r] * inv);
        }
    }
}

// ---------------------------------------------------------------------------
extern "C" void kernel_launch(void* const* d_in, const int* in_sizes, int n_in,
                              void* d_out, int out_size, void* d_ws, size_t ws_size,
                              hipStream_t stream)
{
    const float* x    = (const float*)d_in[0];
    const float* Wq   = (const float*)d_in[1];
    const float* Wk   = (const float*)d_in[2];
    const float* Wv   = (const float*)d_in[3];
    const float* Wo   = (const float*)d_in[4];
    const float* bo   = (const float*)d_in[5];
    const float* W1   = (const float*)d_in[6];
    const float* b1   = (const float*)d_in[7];
    const float* W2   = (const float*)d_in[8];
    const float* b2   = (const float*)d_in[9];
    const float* ln1s = (const float*)d_in[10];
    const float* ln1b = (const float*)d_in[11];
    const float* ln2s = (const float*)d_in[12];
    const float* ln2b = (const float*)d_in[13];

    char* ws = (char*)d_ws;
    // persistent region
    bf16*  W1t  = (bf16*)(ws + 0);          //  8 MB  [4096][1024]
    bf16*  W2t  = (bf16*)(ws + 8388608);    //  8 MB  [1024][4096]
    bf16*  Obuf = (bf16*)(ws + 16777216);   //  4 MB  [2048][1024]
    float* x1   = (float*)(ws + 20971520);  //  8 MB  [2048][1024]
    bf16*  h2   = (bf16*)(ws + 29360128);   //  4 MB  [2048][1024]
    // early region (dead after attention/Oproj) — ff1 aliases its start
    char*  rb    = ws + 33554432;
    bf16*  Wqkvt = (bf16*)(rb + 0);          //  6 MB  [3072][1024]
    bf16*  Wot   = (bf16*)(rb + 6291456);    //  2 MB  [1024][1024]
    bf16*  hbuf  = (bf16*)(rb + 8388608);    //  4 MB  [2048][1024]
    bf16*  QKV   = (bf16*)(rb + 12582912);   // 12 MB  [2048][3072]
    bf16*  Vt    = (bf16*)(rb + 25165824);   //  4 MB  [16][64][2048]
    bf16*  ff1   = (bf16*)(rb + 0);          // 16 MB  [2048][4096] (aliases, safe)

    const dim3 tb(32, 8);
    // weight transpose-casts (B^T layout, bf16)
    transpose_cast_kernel<<<dim3(2, 32, 16), tb, 0, stream>>>(Wq, Wqkvt,              1024, 64,   65536, 65536);
    transpose_cast_kernel<<<dim3(2, 32, 16), tb, 0, stream>>>(Wk, Wqkvt + 1024*1024,  1024, 64,   65536, 65536);
    transpose_cast_kernel<<<dim3(2, 32, 16), tb, 0, stream>>>(Wv, Wqkvt + 2048*1024,  1024, 64,   65536, 65536);
    transpose_cast_kernel<<<dim3(32, 32, 1), tb, 0, stream>>>(Wo, Wot, 1024, 1024, 0, 0);
    transpose_cast_kernel<<<dim3(128, 32, 1), tb, 0, stream>>>(W1, W1t, 1024, 4096, 0, 0);
    transpose_cast_kernel<<<dim3(32, 128, 1), tb, 0, stream>>>(W2, W2t, 4096, 1024, 0, 0);

    ln_kernel<<<2048, 256, 0, stream>>>(x, ln1s, ln1b, hbuf);
    gemm_kernel<0,128,128,4,4,2><<<dim3(24, 16), 256, 0, stream>>>(hbuf, Wqkvt, 3072, 1024, nullptr, QKV, nullptr, nullptr);
    transpose_head_kernel<<<dim3(2, 64, 16), tb, 0, stream>>>(QKV, Vt, 2048);
    attn_kernel<<<dim3(16, 16), 256, 0, stream>>>(QKV, Vt, Obuf);
    gemm_kernel<1,64,128,2,4,2><<<dim3(8, 32), 256, 0, stream>>>(Obuf, Wot, 1024, 1024, x1, nullptr, bo, x);
    ln_kernel<<<2048, 256, 0, stream>>>(x1, ln2s, ln2b, h2);
    gemm_kernel<2,128,128,4,4,2><<<dim3(32, 16), 256, 0, stream>>>(h2, W1t, 4096, 1024, nullptr, ff1, b1, nullptr);
    gemm_kernel<1,64,128,2,4,2><<<dim3(8, 32), 256, 0, stream>>>(ff1, W2t, 1024, 4096, (float*)d_out, nullptr, b2, x1);
}

// Round 4
// 311.600 us; speedup vs baseline: 2.5655x; 1.1248x over previous
//
#include <hip/hip_runtime.h>
#include <cstdint>

// T=2048, D=1024, H=16, HS=64, DFF=4096. fp32 in/out, bf16 MFMA internally.

typedef __bf16 bf16;
typedef __bf16 bf16x4 __attribute__((ext_vector_type(4)));
typedef __bf16 bf16x8 __attribute__((ext_vector_type(8)));
typedef float floatx4 __attribute__((ext_vector_type(4)));

// async global->LDS 16B/lane. LDS dest is wave-uniform base + lane*16 (HW rule).
__device__ __forceinline__ void ld_g2l(const bf16* g, bf16* l) {
    __builtin_amdgcn_global_load_lds(
        (const __attribute__((address_space(1))) void*)g,
        (__attribute__((address_space(3))) void*)l, 16, 0, 0);
}

// ---------------------------------------------------------------------------
// Tiled transpose + fp32->bf16 cast:  dst[c][r] = (bf16)src[r][c], batched.
// ---------------------------------------------------------------------------
__global__ __launch_bounds__(256) void transpose_cast_kernel(
    const float* __restrict__ src, bf16* __restrict__ dst,
    int R, int C, long long sBatch, long long dBatch)
{
    __shared__ float tile[32][33];
    const int tx = threadIdx.x, ty = threadIdx.y;
    src += (size_t)blockIdx.z * sBatch;
    dst += (size_t)blockIdx.z * dBatch;
    const int c0 = blockIdx.x * 32, r0 = blockIdx.y * 32;
#pragma unroll
    for (int i = ty; i < 32; i += 8)
        tile[i][tx] = src[(size_t)(r0 + i) * C + c0 + tx];
    __syncthreads();
#pragma unroll
    for (int i = ty; i < 32; i += 8)
        dst[(size_t)(c0 + i) * R + r0 + tx] = (bf16)tile[tx][i];
}

// ---------------------------------------------------------------------------
// Head-transpose from QKV: dst[h][j][s] = qkv[s][colOff + h*64 + j]   (bf16)
// ---------------------------------------------------------------------------
__global__ __launch_bounds__(256) void transpose_head_kernel(
    const bf16* __restrict__ qkv, bf16* __restrict__ dst, int colOff)
{
    __shared__ bf16 tile[32][33];
    const int tx = threadIdx.x, ty = threadIdx.y;
    const int h = blockIdx.z;
    const int j0 = blockIdx.x * 32, s0 = blockIdx.y * 32;
#pragma unroll
    for (int i = ty; i < 32; i += 8)
        tile[i][tx] = qkv[(size_t)(s0 + i) * 3072 + colOff + h * 64 + j0 + tx];
    __syncthreads();
#pragma unroll
    for (int i = ty; i < 32; i += 8)
        dst[(size_t)h * 64 * 2048 + (size_t)(j0 + i) * 2048 + s0 + tx] = tile[tx][i];
}

// ---------------------------------------------------------------------------
// Row LayerNorm over D=1024: fp32 in -> bf16 out. One block (256 thr) per row.
// ---------------------------------------------------------------------------
__global__ __launch_bounds__(256) void ln_kernel(
    const float* __restrict__ x, const float* __restrict__ sc,
    const float* __restrict__ bi, bf16* __restrict__ out)
{
    const int row = blockIdx.x;
    const int tid = threadIdx.x;
    const float4 v = ((const float4*)(x + (size_t)row * 1024))[tid];
    float s1 = v.x + v.y + v.z + v.w;
    float s2 = v.x * v.x + v.y * v.y + v.z * v.z + v.w * v.w;
#pragma unroll
    for (int mm = 1; mm < 64; mm <<= 1) {
        s1 += __shfl_xor(s1, mm);
        s2 += __shfl_xor(s2, mm);
    }
    __shared__ float w1[4], w2[4];
    const int wave = tid >> 6, lane = tid & 63;
    if (lane == 0) { w1[wave] = s1; w2[wave] = s2; }
    __syncthreads();
    s1 = w1[0] + w1[1] + w1[2] + w1[3];
    s2 = w2[0] + w2[1] + w2[2] + w2[3];
    const float mu = s1 * (1.f / 1024.f);
    const float var = fmaxf(s2 * (1.f / 1024.f) - mu * mu, 0.f);
    const float rr = rsqrtf(var + 1e-6f);
    const float4 scv = ((const float4*)sc)[tid];
    const float4 biv = ((const float4*)bi)[tid];
    bf16x4 ov;
    ov[0] = (bf16)((v.x - mu) * rr * scv.x + biv.x);
    ov[1] = (bf16)((v.y - mu) * rr * scv.y + biv.y);
    ov[2] = (bf16)((v.z - mu) * rr * scv.z + biv.z);
    ov[3] = (bf16)((v.w - mu) * rr * scv.w + biv.w);
    *(bf16x4*)(out + (size_t)row * 1024 + tid * 4) = ov;
}

// ---------------------------------------------------------------------------
// Split-K reduce:  out = p0 + p1 + bias[col] + res   (fp32, 2048x1024)
// ---------------------------------------------------------------------------
__global__ __launch_bounds__(256) void reduce_kernel(
    const float* __restrict__ p0, const float* __restrict__ p1,
    const float* __restrict__ bias, const float* __restrict__ res,
    float* __restrict__ out)
{
    const int idx = blockIdx.x * 256 + threadIdx.x;
    const int c4 = idx & 255;
    const float4 a = ((const float4*)p0)[idx];
    const float4 b = ((const float4*)p1)[idx];
    const float4 bi = ((const float4*)bias)[c4];
    const float4 r = ((const float4*)res)[idx];
    float4 o;
    o.x = a.x + b.x + bi.x + r.x;
    o.y = a.y + b.y + bi.y + r.y;
    o.z = a.z + b.z + bi.z + r.z;
    o.w = a.w + b.w + bi.w + r.w;
    ((float4*)out)[idx] = o;
}

// ---------------------------------------------------------------------------
// bf16 MFMA GEMM:  C[M][N] = A[M][K] * Bt[N][K]^T.  Double-buffered LDS via
// global_load_lds w=16; bank-swizzled staging (lane l fetches k-chunk
// ((l&3)-(l>>3))&3; fragments read chunk (quad+(r15>>1))&3 -> 2-way max).
// MODE 0: outB=(bf16)acc | 1: outF=acc+bias+res | 2: outB=relu(acc+bias)
// MODE 3: split-K partial -> (z==0 ? outF : outF2)
// ---------------------------------------------------------------------------
template <int MODE, int BM, int BN, int MI, int MJ, int WGX, int SPLITK>
__global__ __launch_bounds__(256) void gemm_kernel(
    const bf16* __restrict__ A, const bf16* __restrict__ Bt,
    int N, int K,
    float* __restrict__ outF, float* __restrict__ outF2,
    bf16* __restrict__ outB,
    const float* __restrict__ bias, const float* __restrict__ res)
{
    __shared__ __align__(16) bf16 Alds[2][BM][32];
    __shared__ __align__(16) bf16 Blds[2][BN][32];
    const int tid  = threadIdx.x;
    const int lane = tid & 63;
    const int w    = tid >> 6;
    const int wm = (w / WGX) * (MI * 16);
    const int wn = (w % WGX) * (MJ * 16);
    const int bm = blockIdx.y * BM;
    const int bn = blockIdx.x * BN;
    const int r15  = lane & 15;
    const int quad = lane >> 4;
    const int srow = tid >> 2;
    const int gch  = ((lane & 3) - ((lane >> 3) & 3)) & 3;

    floatx4 acc[MI][MJ];
#pragma unroll
    for (int i = 0; i < MI; ++i)
#pragma unroll
        for (int j = 0; j < MJ; ++j) acc[i][j] = (floatx4)(0.f);

    const int KS    = K / SPLITK;
    const int kBase = (SPLITK > 1) ? (int)blockIdx.z * KS : 0;
    const int nIter = KS / 32;

    const bf16* aptr = A + (size_t)(bm + srow) * K + kBase + gch * 8;
    const bf16* bptr = Bt + (size_t)(bn + srow) * K + kBase + gch * 8;

#pragma unroll
    for (int rr = 0; rr < BM / 64; ++rr)
        ld_g2l(aptr + (size_t)rr * 64 * K, &Alds[0][w * 16 + rr * 64][0]);
#pragma unroll
    for (int rr = 0; rr < BN / 64; ++rr)
        ld_g2l(bptr + (size_t)rr * 64 * K, &Blds[0][w * 16 + rr * 64][0]);

    const int csw = ((quad + (r15 >> 1)) & 3) * 8;

    for (int i = 0; i < nIter; ++i) {
        const int buf = i & 1;
        __syncthreads();   // drains vmcnt -> buf ready; prior reads of buf^1 done
        if (i + 1 < nIter) {
            const int k2 = (i + 1) * 32;
#pragma unroll
            for (int rr = 0; rr < BM / 64; ++rr)
                ld_g2l(aptr + (size_t)rr * 64 * K + k2, &Alds[buf ^ 1][w * 16 + rr * 64][0]);
#pragma unroll
            for (int rr = 0; rr < BN / 64; ++rr)
                ld_g2l(bptr + (size_t)rr * 64 * K + k2, &Blds[buf ^ 1][w * 16 + rr * 64][0]);
        }
        bf16x8 af[MI], bfr[MJ];
#pragma unroll
        for (int i2 = 0; i2 < MI; ++i2)
            af[i2] = *(const bf16x8*)(&Alds[buf][wm + i2 * 16 + r15][csw]);
#pragma unroll
        for (int j = 0; j < MJ; ++j)
            bfr[j] = *(const bf16x8*)(&Blds[buf][wn + j * 16 + r15][csw]);
#pragma unroll
        for (int i2 = 0; i2 < MI; ++i2)
#pragma unroll
            for (int j = 0; j < MJ; ++j)
                acc[i2][j] = __builtin_amdgcn_mfma_f32_16x16x32_bf16(
                    af[i2], bfr[j], acc[i2][j], 0, 0, 0);
    }

    // C/D layout (verified m89/m91): col = lane&15, row = (lane>>4)*4 + reg
    const int row0 = bm + wm + quad * 4;
    const int col0 = bn + wn + r15;
    float* po = (MODE == 3 && SPLITK > 1 && blockIdx.z) ? outF2 : outF;
#pragma unroll
    for (int i = 0; i < MI; ++i) {
#pragma unroll
        for (int reg = 0; reg < 4; ++reg) {
            const int row = row0 + i * 16 + reg;
#pragma unroll
            for (int j = 0; j < MJ; ++j) {
                const int col = col0 + j * 16;
                float v = acc[i][j][reg];
                if (MODE == 0) {
                    outB[(size_t)row * N + col] = (bf16)v;
                } else if (MODE == 1) {
                    outF[(size_t)row * N + col] = v + bias[col] + res[(size_t)row * N + col];
                } else if (MODE == 2) {
                    v += bias[col];
                    outB[(size_t)row * N + col] = (bf16)fmaxf(v, 0.f);
                } else {
                    po[(size_t)row * N + col] = v;
                }
            }
        }
    }
}

// ---------------------------------------------------------------------------
// MFMA flash attention (causal). Block = 4 waves; balanced q-tile pair
// {i, 31-i} (33 key-tile steps). grid (16, H); block 256.
// ---------------------------------------------------------------------------
__global__ __launch_bounds__(256) void attn_kernel(
    const bf16* __restrict__ qkv, const bf16* __restrict__ vt,
    bf16* __restrict__ out)
{
    __shared__ __align__(16) bf16 Qs[64][72];
    __shared__ __align__(16) bf16 Ks[64][72];
    __shared__ __align__(16) bf16 Vs[64][72];
    __shared__ __align__(16) bf16 Ps[4][16][72];

    const int h    = blockIdx.y;
    const int tid  = threadIdx.x;
    const int w    = tid >> 6;
    const int lane = tid & 63;
    const int r15  = lane & 15;
    const int quad = lane >> 4;
    const int sr   = tid >> 2;
    const int sc   = (tid & 3) * 16;

    const bf16* qsec = qkv + h * 64;
    const bf16* ksec = qkv + 1024 + h * 64;
    const bf16* vth  = vt + (size_t)h * 64 * 2048;

#pragma unroll 1
    for (int half = 0; half < 2; ++half) {
        const int qt    = (half == 0) ? (int)blockIdx.x : 31 - (int)blockIdx.x;
        const int qrow0 = qt * 64;

        {
            const bf16* g = qsec + (size_t)(qrow0 + sr) * 3072 + sc;
            const uint4 q0 = *(const uint4*)g;
            const uint4 q1 = *(const uint4*)(g + 8);
            __syncthreads();
            *(uint4*)&Qs[sr][sc]     = q0;
            *(uint4*)&Qs[sr][sc + 8] = q1;
            __syncthreads();
        }
        bf16x8 qf[2];
        qf[0] = *(const bf16x8*)&Qs[w * 16 + r15][quad * 8];
        qf[1] = *(const bf16x8*)&Qs[w * 16 + r15][32 + quad * 8];

        float m[4], l[4];
        floatx4 O[4];
#pragma unroll
        for (int r = 0; r < 4; ++r) { m[r] = -3.0e38f; l[r] = 0.f; }
#pragma unroll
        for (int j = 0; j < 4; ++j) O[j] = (floatx4)(0.f);

#pragma unroll 1
        for (int sb = 0; sb <= qt; ++sb) {
            const int s0 = sb * 64;
            const bf16* gk = ksec + (size_t)(s0 + sr) * 3072 + sc;
            const uint4 k0v = *(const uint4*)gk;
            const uint4 k1v = *(const uint4*)(gk + 8);
            const bf16* gv = vth + (size_t)sr * 2048 + s0 + sc;
            const uint4 v0v = *(const uint4*)gv;
            const uint4 v1v = *(const uint4*)(gv + 8);
            __syncthreads();
            *(uint4*)&Ks[sr][sc]     = k0v;
            *(uint4*)&Ks[sr][sc + 8] = k1v;
            *(uint4*)&Vs[sr][sc]     = v0v;
            *(uint4*)&Vs[sr][sc + 8] = v1v;
            __syncthreads();

            floatx4 S[4];
#pragma unroll
            for (int j = 0; j < 4; ++j) S[j] = (floatx4)(0.f);
#pragma unroll
            for (int c = 0; c < 2; ++c) {
#pragma unroll
                for (int j = 0; j < 4; ++j) {
                    const bf16x8 b = *(const bf16x8*)&Ks[j * 16 + r15][c * 32 + quad * 8];
                    S[j] = __builtin_amdgcn_mfma_f32_16x16x32_bf16(qf[c], b, S[j], 0, 0, 0);
                }
            }
#pragma unroll
            for (int j = 0; j < 4; ++j) {
#pragma unroll
                for (int r = 0; r < 4; ++r) S[j][r] *= 0.125f;
            }
            if (sb == qt) {
                const int rl = w * 16 + quad * 4;
#pragma unroll
                for (int j = 0; j < 4; ++j) {
                    const int col = j * 16 + r15;
#pragma unroll
                    for (int r = 0; r < 4; ++r)
                        if (col > rl + r) S[j][r] = -3.0e38f;
                }
            }
#pragma unroll
            for (int r = 0; r < 4; ++r) {
                float mx = fmaxf(fmaxf(S[0][r], S[1][r]), fmaxf(S[2][r], S[3][r]));
#pragma unroll
                for (int d = 1; d < 16; d <<= 1) mx = fmaxf(mx, __shfl_xor(mx, d));
                const float nm = fmaxf(m[r], mx);
                const float al = __expf(m[r] - nm);
                float sum = 0.f;
#pragma unroll
                for (int j = 0; j < 4; ++j) {
                    const float p = __expf(S[j][r] - nm);
                    S[j][r] = p;
                    sum += p;
                }
#pragma unroll
                for (int d = 1; d < 16; d <<= 1) sum += __shfl_xor(sum, d);
                l[r] = l[r] * al + sum;
                m[r] = nm;
#pragma unroll
                for (int j = 0; j < 4; ++j) O[j][r] *= al;
            }
#pragma unroll
            for (int r = 0; r < 4; ++r)
#pragma unroll
                for (int j = 0; j < 4; ++j)
                    Ps[w][quad * 4 + r][j * 16 + r15] = (bf16)S[j][r];
#pragma unroll
            for (int c = 0; c < 2; ++c) {
                const bf16x8 a = *(const bf16x8*)&Ps[w][r15][c * 32 + quad * 8];
#pragma unroll
                for (int j = 0; j < 4; ++j) {
                    const bf16x8 b = *(const bf16x8*)&Vs[j * 16 + r15][c * 32 + quad * 8];
                    O[j] = __builtin_amdgcn_mfma_f32_16x16x32_bf16(a, b, O[j], 0, 0, 0);
                }
            }
        }
#pragma unroll
        for (int r = 0; r < 4; ++r) {
            const float inv = 1.0f / l[r];
            const int row = qrow0 + w * 16 + quad * 4 + r;
#pragma unroll
            for (int j = 0; j < 4; ++j)
                out[(size_t)row * 1024 + h * 64 + j * 16 + r15] = (bf16)(O[j][r] * inv);
        }
    }
}

// ---------------------------------------------------------------------------
extern "C" void kernel_launch(void* const* d_in, const int* in_sizes, int n_in,
                              void* d_out, int out_size, void* d_ws, size_t ws_size,
                              hipStream_t stream)
{
    const float* x    = (const float*)d_in[0];
    const float* Wq   = (const float*)d_in[1];
    const float* Wk   = (const float*)d_in[2];
    const float* Wv   = (const float*)d_in[3];
    const float* Wo   = (const float*)d_in[4];
    const float* bo   = (const float*)d_in[5];
    const float* W1   = (const float*)d_in[6];
    const float* b1   = (const float*)d_in[7];
    const float* W2   = (const float*)d_in[8];
    const float* b2   = (const float*)d_in[9];
    const float* ln1s = (const float*)d_in[10];
    const float* ln1b = (const float*)d_in[11];
    const float* ln2s = (const float*)d_in[12];
    const float* ln2b = (const float*)d_in[13];

    char* ws = (char*)d_ws;
    bf16*  W1t  = (bf16*)(ws + 0);          //  8 MB (dead after FF1)
    bf16*  W2t  = (bf16*)(ws + 8388608);    //  8 MB
    bf16*  Obuf = (bf16*)(ws + 16777216);   //  4 MB
    float* x1   = (float*)(ws + 20971520);  //  8 MB
    bf16*  h2   = (bf16*)(ws + 29360128);   //  4 MB
    char*  rb    = ws + 33554432;
    bf16*  Wqkvt = (bf16*)(rb + 0);          //  6 MB
    bf16*  Wot   = (bf16*)(rb + 6291456);    //  2 MB
    bf16*  hbuf  = (bf16*)(rb + 8388608);    //  4 MB
    bf16*  QKV   = (bf16*)(rb + 12582912);   // 12 MB
    bf16*  Vt    = (bf16*)(rb + 25165824);   //  4 MB
    bf16*  ff1   = (bf16*)(rb + 0);          // 16 MB (aliases early region)
    float* psumA = (float*)(ws + 0);         //  8 MB over W1t (dead at FF2)
    float* psumB = (float*)(rb + 16777216);  //  8 MB over QKV tail (dead at FF2)

    const dim3 tb(32, 8);
    transpose_cast_kernel<<<dim3(2, 32, 16), tb, 0, stream>>>(Wq, Wqkvt,              1024, 64,   65536, 65536);
    transpose_cast_kernel<<<dim3(2, 32, 16), tb, 0, stream>>>(Wk, Wqkvt + 1024*1024,  1024, 64,   65536, 65536);
    transpose_cast_kernel<<<dim3(2, 32, 16), tb, 0, stream>>>(Wv, Wqkvt + 2048*1024,  1024, 64,   65536, 65536);
    transpose_cast_kernel<<<dim3(32, 32, 1), tb, 0, stream>>>(Wo, Wot, 1024, 1024, 0, 0);
    transpose_cast_kernel<<<dim3(128, 32, 1), tb, 0, stream>>>(W1, W1t, 1024, 4096, 0, 0);
    transpose_cast_kernel<<<dim3(32, 128, 1), tb, 0, stream>>>(W2, W2t, 4096, 1024, 0, 0);

    ln_kernel<<<2048, 256, 0, stream>>>(x, ln1s, ln1b, hbuf);
    // QKV: 64x128 tiles, 768 blocks (3/CU)
    gemm_kernel<0,64,128,2,4,2,1><<<dim3(24, 32), 256, 0, stream>>>(hbuf, Wqkvt, 3072, 1024, nullptr, nullptr, QKV, nullptr, nullptr);
    transpose_head_kernel<<<dim3(2, 64, 16), tb, 0, stream>>>(QKV, Vt, 2048);
    attn_kernel<<<dim3(16, 16), 256, 0, stream>>>(QKV, Vt, Obuf);
    // Oproj: 64x64 tiles, 512 blocks (2/CU)
    gemm_kernel<1,64,64,2,2,2,1><<<dim3(16, 32), 256, 0, stream>>>(Obuf, Wot, 1024, 1024, x1, nullptr, nullptr, bo, x);
    ln_kernel<<<2048, 256, 0, stream>>>(x1, ln2s, ln2b, h2);
    // FF1: 64x128 tiles, 1024 blocks (4/CU)
    gemm_kernel<2,64,128,2,4,2,1><<<dim3(32, 32), 256, 0, stream>>>(h2, W1t, 4096, 1024, nullptr, nullptr, ff1, b1, nullptr);
    // FF2: 64x128 tiles, split-K=2, 512 blocks (2/CU) -> psumA/psumB
    gemm_kernel<3,64,128,2,4,2,2><<<dim3(8, 32, 2), 256, 0, stream>>>(ff1, W2t, 1024, 4096, psumA, psumB, nullptr, nullptr, nullptr);
    reduce_kernel<<<2048, 256, 0, stream>>>(psumA, psumB, b2, x1, (float*)d_out);
}

// Round 5
// 290.459 us; speedup vs baseline: 2.7522x; 1.0728x over previous
//
#include <hip/hip_runtime.h>
#include <cstdint>

// T=2048, D=1024, H=16, HS=64, DFF=4096. fp32 in/out, bf16 MFMA internally.

typedef __bf16 bf16;
typedef __bf16 bf16x4 __attribute__((ext_vector_type(4)));
typedef __bf16 bf16x8 __attribute__((ext_vector_type(8)));
typedef float floatx4 __attribute__((ext_vector_type(4)));

// async global->LDS 16B/lane. LDS dest is wave-uniform base + lane*16 (HW rule).
__device__ __forceinline__ void ld_g2l(const bf16* g, bf16* l) {
    __builtin_amdgcn_global_load_lds(
        (const __attribute__((address_space(1))) void*)g,
        (__attribute__((address_space(3))) void*)l, 16, 0, 0);
}

// ---------------------------------------------------------------------------
// Tiled transpose + fp32->bf16 cast:  dst[c][r] = (bf16)src[r][c], batched.
// ---------------------------------------------------------------------------
__global__ __launch_bounds__(256) void transpose_cast_kernel(
    const float* __restrict__ src, bf16* __restrict__ dst,
    int R, int C, long long sBatch, long long dBatch)
{
    __shared__ float tile[32][33];
    const int tx = threadIdx.x, ty = threadIdx.y;
    src += (size_t)blockIdx.z * sBatch;
    dst += (size_t)blockIdx.z * dBatch;
    const int c0 = blockIdx.x * 32, r0 = blockIdx.y * 32;
#pragma unroll
    for (int i = ty; i < 32; i += 8)
        tile[i][tx] = src[(size_t)(r0 + i) * C + c0 + tx];
    __syncthreads();
#pragma unroll
    for (int i = ty; i < 32; i += 8)
        dst[(size_t)(c0 + i) * R + r0 + tx] = (bf16)tile[tx][i];
}

// ---------------------------------------------------------------------------
// Head-transpose from QKV: dst[h][j][s] = qkv[s][colOff + h*64 + j]   (bf16)
// ---------------------------------------------------------------------------
__global__ __launch_bounds__(256) void transpose_head_kernel(
    const bf16* __restrict__ qkv, bf16* __restrict__ dst, int colOff)
{
    __shared__ bf16 tile[32][33];
    const int tx = threadIdx.x, ty = threadIdx.y;
    const int h = blockIdx.z;
    const int j0 = blockIdx.x * 32, s0 = blockIdx.y * 32;
#pragma unroll
    for (int i = ty; i < 32; i += 8)
        tile[i][tx] = qkv[(size_t)(s0 + i) * 3072 + colOff + h * 64 + j0 + tx];
    __syncthreads();
#pragma unroll
    for (int i = ty; i < 32; i += 8)
        dst[(size_t)h * 64 * 2048 + (size_t)(j0 + i) * 2048 + s0 + tx] = tile[tx][i];
}

// ---------------------------------------------------------------------------
// Row LayerNorm over D=1024: fp32 in -> bf16 out. One block (256 thr) per row.
// ---------------------------------------------------------------------------
__global__ __launch_bounds__(256) void ln_kernel(
    const float* __restrict__ x, const float* __restrict__ sc,
    const float* __restrict__ bi, bf16* __restrict__ out)
{
    const int row = blockIdx.x;
    const int tid = threadIdx.x;
    const float4 v = ((const float4*)(x + (size_t)row * 1024))[tid];
    float s1 = v.x + v.y + v.z + v.w;
    float s2 = v.x * v.x + v.y * v.y + v.z * v.z + v.w * v.w;
#pragma unroll
    for (int mm = 1; mm < 64; mm <<= 1) {
        s1 += __shfl_xor(s1, mm);
        s2 += __shfl_xor(s2, mm);
    }
    __shared__ float w1[4], w2[4];
    const int wave = tid >> 6, lane = tid & 63;
    if (lane == 0) { w1[wave] = s1; w2[wave] = s2; }
    __syncthreads();
    s1 = w1[0] + w1[1] + w1[2] + w1[3];
    s2 = w2[0] + w2[1] + w2[2] + w2[3];
    const float mu = s1 * (1.f / 1024.f);
    const float var = fmaxf(s2 * (1.f / 1024.f) - mu * mu, 0.f);
    const float rr = rsqrtf(var + 1e-6f);
    const float4 scv = ((const float4*)sc)[tid];
    const float4 biv = ((const float4*)bi)[tid];
    bf16x4 ov;
    ov[0] = (bf16)((v.x - mu) * rr * scv.x + biv.x);
    ov[1] = (bf16)((v.y - mu) * rr * scv.y + biv.y);
    ov[2] = (bf16)((v.z - mu) * rr * scv.z + biv.z);
    ov[3] = (bf16)((v.w - mu) * rr * scv.w + biv.w);
    *(bf16x4*)(out + (size_t)row * 1024 + tid * 4) = ov;
}

// ---------------------------------------------------------------------------
// Split-K reduce:  out = p0 + p1 + bias[col] + res   (fp32, 2048x1024)
// ---------------------------------------------------------------------------
__global__ __launch_bounds__(256) void reduce_kernel(
    const float* __restrict__ p0, const float* __restrict__ p1,
    const float* __restrict__ bias, const float* __restrict__ res,
    float* __restrict__ out)
{
    const int idx = blockIdx.x * 256 + threadIdx.x;
    const int c4 = idx & 255;
    const float4 a = ((const float4*)p0)[idx];
    const float4 b = ((const float4*)p1)[idx];
    const float4 bi = ((const float4*)bias)[c4];
    const float4 r = ((const float4*)res)[idx];
    float4 o;
    o.x = a.x + b.x + bi.x + r.x;
    o.y = a.y + b.y + bi.y + r.y;
    o.z = a.z + b.z + bi.z + r.z;
    o.w = a.w + b.w + bi.w + r.w;
    ((float4*)out)[idx] = o;
}

// ---------------------------------------------------------------------------
// bf16 MFMA GEMM:  C[M][N] = A[M][K] * Bt[N][K]^T.  Double-buffered LDS via
// global_load_lds w=16; bank-swizzled staging.
// MODE 0: outB=(bf16)acc | 1: outF=acc+bias+res | 2: outB=relu(acc+bias)
// MODE 3: split-K partial -> (z==0 ? outF : outF2)
// ---------------------------------------------------------------------------
template <int MODE, int BM, int BN, int MI, int MJ, int WGX, int SPLITK>
__global__ __launch_bounds__(256) void gemm_kernel(
    const bf16* __restrict__ A, const bf16* __restrict__ Bt,
    int N, int K,
    float* __restrict__ outF, float* __restrict__ outF2,
    bf16* __restrict__ outB,
    const float* __restrict__ bias, const float* __restrict__ res)
{
    __shared__ __align__(16) bf16 Alds[2][BM][32];
    __shared__ __align__(16) bf16 Blds[2][BN][32];
    const int tid  = threadIdx.x;
    const int lane = tid & 63;
    const int w    = tid >> 6;
    const int wm = (w / WGX) * (MI * 16);
    const int wn = (w % WGX) * (MJ * 16);
    const int bm = blockIdx.y * BM;
    const int bn = blockIdx.x * BN;
    const int r15  = lane & 15;
    const int quad = lane >> 4;
    const int srow = tid >> 2;
    const int gch  = ((lane & 3) - ((lane >> 3) & 3)) & 3;

    floatx4 acc[MI][MJ];
#pragma unroll
    for (int i = 0; i < MI; ++i)
#pragma unroll
        for (int j = 0; j < MJ; ++j) acc[i][j] = (floatx4)(0.f);

    const int KS    = K / SPLITK;
    const int kBase = (SPLITK > 1) ? (int)blockIdx.z * KS : 0;
    const int nIter = KS / 32;

    const bf16* aptr = A + (size_t)(bm + srow) * K + kBase + gch * 8;
    const bf16* bptr = Bt + (size_t)(bn + srow) * K + kBase + gch * 8;

#pragma unroll
    for (int rr = 0; rr < BM / 64; ++rr)
        ld_g2l(aptr + (size_t)rr * 64 * K, &Alds[0][w * 16 + rr * 64][0]);
#pragma unroll
    for (int rr = 0; rr < BN / 64; ++rr)
        ld_g2l(bptr + (size_t)rr * 64 * K, &Blds[0][w * 16 + rr * 64][0]);

    const int csw = ((quad + (r15 >> 1)) & 3) * 8;

    for (int i = 0; i < nIter; ++i) {
        const int buf = i & 1;
        __syncthreads();   // drains vmcnt -> buf ready; prior reads of buf^1 done
        if (i + 1 < nIter) {
            const int k2 = (i + 1) * 32;
#pragma unroll
            for (int rr = 0; rr < BM / 64; ++rr)
                ld_g2l(aptr + (size_t)rr * 64 * K + k2, &Alds[buf ^ 1][w * 16 + rr * 64][0]);
#pragma unroll
            for (int rr = 0; rr < BN / 64; ++rr)
                ld_g2l(bptr + (size_t)rr * 64 * K + k2, &Blds[buf ^ 1][w * 16 + rr * 64][0]);
        }
        bf16x8 af[MI], bfr[MJ];
#pragma unroll
        for (int i2 = 0; i2 < MI; ++i2)
            af[i2] = *(const bf16x8*)(&Alds[buf][wm + i2 * 16 + r15][csw]);
#pragma unroll
        for (int j = 0; j < MJ; ++j)
            bfr[j] = *(const bf16x8*)(&Blds[buf][wn + j * 16 + r15][csw]);
#pragma unroll
        for (int i2 = 0; i2 < MI; ++i2)
#pragma unroll
            for (int j = 0; j < MJ; ++j)
                acc[i2][j] = __builtin_amdgcn_mfma_f32_16x16x32_bf16(
                    af[i2], bfr[j], acc[i2][j], 0, 0, 0);
    }

    // C/D layout (verified m89/m91): col = lane&15, row = (lane>>4)*4 + reg
    const int row0 = bm + wm + quad * 4;
    const int col0 = bn + wn + r15;
    float* po = (MODE == 3 && SPLITK > 1 && blockIdx.z) ? outF2 : outF;
#pragma unroll
    for (int i = 0; i < MI; ++i) {
#pragma unroll
        for (int reg = 0; reg < 4; ++reg) {
            const int row = row0 + i * 16 + reg;
#pragma unroll
            for (int j = 0; j < MJ; ++j) {
                const int col = col0 + j * 16;
                float v = acc[i][j][reg];
                if (MODE == 0) {
                    outB[(size_t)row * N + col] = (bf16)v;
                } else if (MODE == 1) {
                    outF[(size_t)row * N + col] = v + bias[col] + res[(size_t)row * N + col];
                } else if (MODE == 2) {
                    v += bias[col];
                    outB[(size_t)row * N + col] = (bf16)fmaxf(v, 0.f);
                } else {
                    po[(size_t)row * N + col] = v;
                }
            }
        }
    }
}

// ---------------------------------------------------------------------------
// MFMA flash attention (causal), fixed-offset softmax (no online max):
//   p = exp2(S * 0.125*log2e - 28.854)  -> O,l accumulate LINEARLY.
// Async dbuf K/V staging via global_load_lds into XOR-swizzled unpadded
// [64][64] tiles: LDS chunk c holds global chunk c^(row&7); fragment reads
// chunk (c*4+quad)^(r15&7) -> 2-way bank aliasing (free, m136).
// Block = 4 waves; balanced q-tile pair {i, 31-i}; grid (16, H).
// ---------------------------------------------------------------------------
__global__ __launch_bounds__(256) void attn_kernel(
    const bf16* __restrict__ qkv, const bf16* __restrict__ vt,
    bf16* __restrict__ out)
{
    __shared__ __align__(16) bf16 Qs[64][64];
    __shared__ __align__(16) bf16 Ks[2][64][64];
    __shared__ __align__(16) bf16 Vs[2][64][64];
    __shared__ __align__(16) bf16 Ps[4][16][72];

    const int h    = blockIdx.y;
    const int tid  = threadIdx.x;
    const int w    = tid >> 6;
    const int lane = tid & 63;
    const int r15  = lane & 15;
    const int quad = lane >> 4;
    const int rl   = lane >> 3;                   // 0..7 row in 8-row group
    const int gsw  = (lane & 7) ^ (rl & 7);       // swizzled global chunk

    const bf16* qsec = qkv + h * 64;
    const bf16* ksec = qkv + 1024 + h * 64;
    const bf16* vth  = vt + (size_t)h * 64 * 2048;

#pragma unroll 1
    for (int half = 0; half < 2; ++half) {
        const int qt    = (half == 0) ? (int)blockIdx.x : 31 - (int)blockIdx.x;
        const int qrow0 = qt * 64;

        // stage Q (swizzled, g2l) + prefetch K/V step 0 into buf 0
#pragma unroll
        for (int t = 0; t < 2; ++t) {
            const int r = t * 32 + w * 8 + rl;
            ld_g2l(qsec + (size_t)(qrow0 + r) * 3072 + gsw * 8, &Qs[t * 32 + w * 8][0]);
            ld_g2l(ksec + (size_t)r * 3072 + gsw * 8, &Ks[0][t * 32 + w * 8][0]);
            ld_g2l(vth + (size_t)r * 2048 + gsw * 8, &Vs[0][t * 32 + w * 8][0]);
        }
        __syncthreads();   // all staging landed

        bf16x8 qf[2];
#pragma unroll
        for (int c = 0; c < 2; ++c) {
            const int p = ((c * 4 + quad) ^ (r15 & 7)) * 8;
            qf[c] = *(const bf16x8*)&Qs[w * 16 + r15][p];
        }

        float lacc[4] = {0.f, 0.f, 0.f, 0.f};
        floatx4 O[4];
#pragma unroll
        for (int j = 0; j < 4; ++j) O[j] = (floatx4)(0.f);

#pragma unroll 1
        for (int sb = 0; sb <= qt; ++sb) {
            const int buf = sb & 1;
            if (sb < qt) {   // prefetch next K/V into buf^1
                const int s1 = (sb + 1) * 64;
#pragma unroll
                for (int t = 0; t < 2; ++t) {
                    const int r = t * 32 + w * 8 + rl;
                    ld_g2l(ksec + (size_t)(s1 + r) * 3072 + gsw * 8, &Ks[buf ^ 1][t * 32 + w * 8][0]);
                    ld_g2l(vth + (size_t)r * 2048 + s1 + gsw * 8, &Vs[buf ^ 1][t * 32 + w * 8][0]);
                }
            }

            // S = Q K^T  (wave's 16 rows x 64 keys)
            floatx4 S[4];
#pragma unroll
            for (int j = 0; j < 4; ++j) S[j] = (floatx4)(0.f);
#pragma unroll
            for (int c = 0; c < 2; ++c) {
#pragma unroll
                for (int j = 0; j < 4; ++j) {
                    const int p = ((c * 4 + quad) ^ (r15 & 7)) * 8;
                    const bf16x8 b = *(const bf16x8*)&Ks[buf][j * 16 + r15][p];
                    S[j] = __builtin_amdgcn_mfma_f32_16x16x32_bf16(qf[c], b, S[j], 0, 0, 0);
                }
            }
            // fixed-offset softmax: p = exp2(S*0.125*log2e - 28.854)
            const bool diag = (sb == qt);
            const int rowl = w * 16 + quad * 4;
#pragma unroll
            for (int j = 0; j < 4; ++j) {
                const int col = j * 16 + r15;
#pragma unroll
                for (int r = 0; r < 4; ++r) {
                    float p = exp2f(fmaf(S[j][r], 0.18033688f, -28.853901f));
                    if (diag && col > rowl + r) p = 0.f;
                    S[j][r] = p;
                    lacc[r] += p;
                }
            }
            // P: C-layout -> A-layout via LDS (per-wave region, no barrier)
#pragma unroll
            for (int r = 0; r < 4; ++r)
#pragma unroll
                for (int j = 0; j < 4; ++j)
                    Ps[w][quad * 4 + r][j * 16 + r15] = (bf16)S[j][r];
            // O += P V
#pragma unroll
            for (int c = 0; c < 2; ++c) {
                const bf16x8 a = *(const bf16x8*)&Ps[w][r15][c * 32 + quad * 8];
#pragma unroll
                for (int j = 0; j < 4; ++j) {
                    const int p = ((c * 4 + quad) ^ (r15 & 7)) * 8;
                    const bf16x8 b = *(const bf16x8*)&Vs[buf][j * 16 + r15][p];
                    O[j] = __builtin_amdgcn_mfma_f32_16x16x32_bf16(a, b, O[j], 0, 0, 0);
                }
            }
            __syncthreads();  // drain prefetch (vmcnt) + protect buf reuse
        }
        // reduce l across the 16-lane row group (once per tile)
#pragma unroll
        for (int r = 0; r < 4; ++r) {
#pragma unroll
            for (int d = 1; d < 16; d <<= 1) lacc[r] += __shfl_xor(lacc[r], d);
        }
        // epilogue: out[q][h*64+dim] = O / l
#pragma unroll
        for (int r = 0; r < 4; ++r) {
            const float inv = 1.0f / lacc[r];
            const int row = qrow0 + w * 16 + quad * 4 + r;
#pragma unroll
            for (int j = 0; j < 4; ++j)
                out[(size_t)row * 1024 + h * 64 + j * 16 + r15] = (bf16)(O[j][r] * inv);
        }
    }
}

// ---------------------------------------------------------------------------
extern "C" void kernel_launch(void* const* d_in, const int* in_sizes, int n_in,
                              void* d_out, int out_size, void* d_ws, size_t ws_size,
                              hipStream_t stream)
{
    const float* x    = (const float*)d_in[0];
    const float* Wq   = (const float*)d_in[1];
    const float* Wk   = (const float*)d_in[2];
    const float* Wv   = (const float*)d_in[3];
    const float* Wo   = (const float*)d_in[4];
    const float* bo   = (const float*)d_in[5];
    const float* W1   = (const float*)d_in[6];
    const float* b1   = (const float*)d_in[7];
    const float* W2   = (const float*)d_in[8];
    const float* b2   = (const float*)d_in[9];
    const float* ln1s = (const float*)d_in[10];
    const float* ln1b = (const float*)d_in[11];
    const float* ln2s = (const float*)d_in[12];
    const float* ln2b = (const float*)d_in[13];

    char* ws = (char*)d_ws;
    bf16*  W1t  = (bf16*)(ws + 0);          //  8 MB (dead after FF1)
    bf16*  W2t  = (bf16*)(ws + 8388608);    //  8 MB
    bf16*  Obuf = (bf16*)(ws + 16777216);   //  4 MB
    float* x1   = (float*)(ws + 20971520);  //  8 MB
    bf16*  h2   = (bf16*)(ws + 29360128);   //  4 MB
    char*  rb    = ws + 33554432;
    bf16*  Wqkvt = (bf16*)(rb + 0);          //  6 MB
    bf16*  Wot   = (bf16*)(rb + 6291456);    //  2 MB
    bf16*  hbuf  = (bf16*)(rb + 8388608);    //  4 MB
    bf16*  QKV   = (bf16*)(rb + 12582912);   // 12 MB
    bf16*  Vt    = (bf16*)(rb + 25165824);   //  4 MB
    bf16*  ff1   = (bf16*)(rb + 0);          // 16 MB (aliases early region)
    float* psumA = (float*)(ws + 0);         //  8 MB over W1t (dead at FF2)
    float* psumB = (float*)(rb + 16777216);  //  8 MB over QKV tail (dead at FF2)

    const dim3 tb(32, 8);
    transpose_cast_kernel<<<dim3(2, 32, 16), tb, 0, stream>>>(Wq, Wqkvt,              1024, 64,   65536, 65536);
    transpose_cast_kernel<<<dim3(2, 32, 16), tb, 0, stream>>>(Wk, Wqkvt + 1024*1024,  1024, 64,   65536, 65536);
    transpose_cast_kernel<<<dim3(2, 32, 16), tb, 0, stream>>>(Wv, Wqkvt + 2048*1024,  1024, 64,   65536, 65536);
    transpose_cast_kernel<<<dim3(32, 32, 1), tb, 0, stream>>>(Wo, Wot, 1024, 1024, 0, 0);
    transpose_cast_kernel<<<dim3(128, 32, 1), tb, 0, stream>>>(W1, W1t, 1024, 4096, 0, 0);
    transpose_cast_kernel<<<dim3(32, 128, 1), tb, 0, stream>>>(W2, W2t, 4096, 1024, 0, 0);

    ln_kernel<<<2048, 256, 0, stream>>>(x, ln1s, ln1b, hbuf);
    // QKV: 64x128 tiles, 768 blocks (3/CU)
    gemm_kernel<0,64,128,2,4,2,1><<<dim3(24, 32), 256, 0, stream>>>(hbuf, Wqkvt, 3072, 1024, nullptr, nullptr, QKV, nullptr, nullptr);
    transpose_head_kernel<<<dim3(2, 64, 16), tb, 0, stream>>>(QKV, Vt, 2048);
    attn_kernel<<<dim3(16, 16), 256, 0, stream>>>(QKV, Vt, Obuf);
    // Oproj: 64x64 tiles, 512 blocks (2/CU)
    gemm_kernel<1,64,64,2,2,2,1><<<dim3(16, 32), 256, 0, stream>>>(Obuf, Wot, 1024, 1024, x1, nullptr, nullptr, bo, x);
    ln_kernel<<<2048, 256, 0, stream>>>(x1, ln2s, ln2b, h2);
    // FF1: 64x128 tiles, 1024 blocks (4/CU)
    gemm_kernel<2,64,128,2,4,2,1><<<dim3(32, 32), 256, 0, stream>>>(h2, W1t, 4096, 1024, nullptr, nullptr, ff1, b1, nullptr);
    // FF2: 64x128 tiles, split-K=2, 512 blocks (2/CU) -> psumA/psumB
    gemm_kernel<3,64,128,2,4,2,2><<<dim3(8, 32, 2), 256, 0, stream>>>(ff1, W2t, 1024, 4096, psumA, psumB, nullptr, nullptr, nullptr);
    reduce_kernel<<<2048, 256, 0, stream>>>(psumA, psumB, b2, x1, (float*)d_out);
}

// Round 6
// 276.976 us; speedup vs baseline: 2.8862x; 1.0487x over previous
//
#include <hip/hip_runtime.h>
#include <cstdint>

// T=2048, D=1024, H=16, HS=64, DFF=4096. fp32 in/out, bf16 MFMA internally.

typedef __bf16 bf16;
typedef __bf16 bf16x4 __attribute__((ext_vector_type(4)));
typedef __bf16 bf16x8 __attribute__((ext_vector_type(8)));
typedef float floatx4 __attribute__((ext_vector_type(4)));

// async global->LDS 16B/lane. LDS dest is wave-uniform base + lane*16 (HW rule).
__device__ __forceinline__ void ld_g2l(const bf16* g, bf16* l) {
    __builtin_amdgcn_global_load_lds(
        (const __attribute__((address_space(1))) void*)g,
        (__attribute__((address_space(3))) void*)l, 16, 0, 0);
}

// ---------------------------------------------------------------------------
// Tiled transpose + fp32->bf16 cast:  dst[c][r] = (bf16)src[r][c], batched.
// ---------------------------------------------------------------------------
__global__ __launch_bounds__(256) void transpose_cast_kernel(
    const float* __restrict__ src, bf16* __restrict__ dst,
    int R, int C, long long sBatch, long long dBatch)
{
    __shared__ float tile[32][33];
    const int tx = threadIdx.x, ty = threadIdx.y;
    src += (size_t)blockIdx.z * sBatch;
    dst += (size_t)blockIdx.z * dBatch;
    const int c0 = blockIdx.x * 32, r0 = blockIdx.y * 32;
#pragma unroll
    for (int i = ty; i < 32; i += 8)
        tile[i][tx] = src[(size_t)(r0 + i) * C + c0 + tx];
    __syncthreads();
#pragma unroll
    for (int i = ty; i < 32; i += 8)
        dst[(size_t)(c0 + i) * R + r0 + tx] = (bf16)tile[tx][i];
}

// ---------------------------------------------------------------------------
// Head-transpose from QKV: dst[h][j][s] = qkv[s][colOff + h*64 + j]   (bf16)
// ---------------------------------------------------------------------------
__global__ __launch_bounds__(256) void transpose_head_kernel(
    const bf16* __restrict__ qkv, bf16* __restrict__ dst, int colOff)
{
    __shared__ bf16 tile[32][33];
    const int tx = threadIdx.x, ty = threadIdx.y;
    const int h = blockIdx.z;
    const int j0 = blockIdx.x * 32, s0 = blockIdx.y * 32;
#pragma unroll
    for (int i = ty; i < 32; i += 8)
        tile[i][tx] = qkv[(size_t)(s0 + i) * 3072 + colOff + h * 64 + j0 + tx];
    __syncthreads();
#pragma unroll
    for (int i = ty; i < 32; i += 8)
        dst[(size_t)h * 64 * 2048 + (size_t)(j0 + i) * 2048 + s0 + tx] = tile[tx][i];
}

// ---------------------------------------------------------------------------
// Row LayerNorm over D=1024: fp32 in -> bf16 out. One block (256 thr) per row.
// ---------------------------------------------------------------------------
__global__ __launch_bounds__(256) void ln_kernel(
    const float* __restrict__ x, const float* __restrict__ sc,
    const float* __restrict__ bi, bf16* __restrict__ out)
{
    const int row = blockIdx.x;
    const int tid = threadIdx.x;
    const float4 v = ((const float4*)(x + (size_t)row * 1024))[tid];
    float s1 = v.x + v.y + v.z + v.w;
    float s2 = v.x * v.x + v.y * v.y + v.z * v.z + v.w * v.w;
#pragma unroll
    for (int mm = 1; mm < 64; mm <<= 1) {
        s1 += __shfl_xor(s1, mm);
        s2 += __shfl_xor(s2, mm);
    }
    __shared__ float w1[4], w2[4];
    const int wave = tid >> 6, lane = tid & 63;
    if (lane == 0) { w1[wave] = s1; w2[wave] = s2; }
    __syncthreads();
    s1 = w1[0] + w1[1] + w1[2] + w1[3];
    s2 = w2[0] + w2[1] + w2[2] + w2[3];
    const float mu = s1 * (1.f / 1024.f);
    const float var = fmaxf(s2 * (1.f / 1024.f) - mu * mu, 0.f);
    const float rr = rsqrtf(var + 1e-6f);
    const float4 scv = ((const float4*)sc)[tid];
    const float4 biv = ((const float4*)bi)[tid];
    bf16x4 ov;
    ov[0] = (bf16)((v.x - mu) * rr * scv.x + biv.x);
    ov[1] = (bf16)((v.y - mu) * rr * scv.y + biv.y);
    ov[2] = (bf16)((v.z - mu) * rr * scv.z + biv.z);
    ov[3] = (bf16)((v.w - mu) * rr * scv.w + biv.w);
    *(bf16x4*)(out + (size_t)row * 1024 + tid * 4) = ov;
}

// ---------------------------------------------------------------------------
// Split-K reduce:  out = p0 + p1 + bias[col] + res   (fp32, 2048x1024)
// ---------------------------------------------------------------------------
__global__ __launch_bounds__(256) void reduce_kernel(
    const float* __restrict__ p0, const float* __restrict__ p1,
    const float* __restrict__ bias, const float* __restrict__ res,
    float* __restrict__ out)
{
    const int idx = blockIdx.x * 256 + threadIdx.x;
    const int c4 = idx & 255;
    const float4 a = ((const float4*)p0)[idx];
    const float4 b = ((const float4*)p1)[idx];
    const float4 bi = ((const float4*)bias)[c4];
    const float4 r = ((const float4*)res)[idx];
    float4 o;
    o.x = a.x + b.x + bi.x + r.x;
    o.y = a.y + b.y + bi.y + r.y;
    o.z = a.z + b.z + bi.z + r.z;
    o.w = a.w + b.w + bi.w + r.w;
    ((float4*)out)[idx] = o;
}

// ---------------------------------------------------------------------------
// bf16 MFMA GEMM:  C[M][N] = A[M][K] * Bt[N][K]^T.
// BK=64, double-buffered global_load_lds staging into XOR-swizzled unpadded
// [rows][64] tiles (phys chunk = logical ^ (row&7); 2-way banks = free).
// 2D XCD swizzle <NG,MG>: linear-id%8 = XCD gets bn-group (xcd%NG) x bm-group
// (xcd/NG); within XCD bn sweeps fastest -> A tile + B slice stay L2-resident.
// MODE 0: outB=(bf16)acc | 1: outF=acc+bias+res | 2: outB=relu(acc+bias)
// MODE 3: split-K partial -> (z==0 ? outF : outF2)
// ---------------------------------------------------------------------------
template <int MODE, int BM, int BN, int MI, int MJ, int WGX, int SPLITK,
          int NG, int MG>
__global__ __launch_bounds__(256) void gemm_kernel(
    const bf16* __restrict__ A, const bf16* __restrict__ Bt,
    int N, int K,
    float* __restrict__ outF, float* __restrict__ outF2,
    bf16* __restrict__ outB,
    const float* __restrict__ bias, const float* __restrict__ res)
{
    __shared__ __align__(16) bf16 Alds[2][BM][64];
    __shared__ __align__(16) bf16 Blds[2][BN][64];
    const int tid  = threadIdx.x;
    const int lane = tid & 63;
    const int w    = tid >> 6;
    const int r15  = lane & 15;
    const int quad = lane >> 4;

    // XCD-aware block decomposition (id%8 ~ XCD round-robin heuristic)
    const int id    = blockIdx.x + gridDim.x * (blockIdx.y + gridDim.y * blockIdx.z);
    const int xcd   = id & 7;
    const int seq   = id >> 3;
    const int nPerX = gridDim.x / NG;
    const int mPerX = gridDim.y / MG;
    const int nm    = nPerX * mPerX;
    const int z     = seq / nm;
    const int loc   = seq - z * nm;
    const int bn    = ((xcd % NG) * nPerX + (loc % nPerX)) * BN;
    const int bm    = ((xcd / NG) * mPerX + (loc / nPerX)) * BM;

    const int wm = (w / WGX) * (MI * 16);
    const int wn = (w % WGX) * (MJ * 16);

    floatx4 acc[MI][MJ];
#pragma unroll
    for (int i = 0; i < MI; ++i)
#pragma unroll
        for (int j = 0; j < MJ; ++j) acc[i][j] = (floatx4)(0.f);

    const int KS    = K / SPLITK;
    const int kBase = (SPLITK > 1) ? z * KS : 0;
    const int nIter = KS / 64;

    const int lrow = lane >> 3;               // 0..7
    const int gch  = (lane & 7) ^ lrow;       // swizzled k-chunk for staging
    const bf16* aptr = A + (size_t)(bm + w * 16 + lrow) * K + kBase + gch * 8;
    const bf16* bptr = Bt + (size_t)(bn + w * 16 + lrow) * K + kBase + gch * 8;

    // prologue: stage k-block 0 into buffer 0 (2 g2l per 64-row section)
#pragma unroll
    for (int rr = 0; rr < BM / 64; ++rr)
#pragma unroll
        for (int t = 0; t < 2; ++t)
            ld_g2l(aptr + (size_t)(rr * 64 + t * 8) * K, &Alds[0][rr * 64 + w * 16 + t * 8][0]);
#pragma unroll
    for (int rr = 0; rr < BN / 64; ++rr)
#pragma unroll
        for (int t = 0; t < 2; ++t)
            ld_g2l(bptr + (size_t)(rr * 64 + t * 8) * K, &Blds[0][rr * 64 + w * 16 + t * 8][0]);

    for (int it = 0; it < nIter; ++it) {
        const int buf = it & 1;
        __syncthreads();   // drains vmcnt -> buf ready; prior reads of buf^1 done
        if (it + 1 < nIter) {
            const int k2 = (it + 1) * 64;
#pragma unroll
            for (int rr = 0; rr < BM / 64; ++rr)
#pragma unroll
                for (int t = 0; t < 2; ++t)
                    ld_g2l(aptr + (size_t)(rr * 64 + t * 8) * K + k2,
                           &Alds[buf ^ 1][rr * 64 + w * 16 + t * 8][0]);
#pragma unroll
            for (int rr = 0; rr < BN / 64; ++rr)
#pragma unroll
                for (int t = 0; t < 2; ++t)
                    ld_g2l(bptr + (size_t)(rr * 64 + t * 8) * K + k2,
                           &Blds[buf ^ 1][rr * 64 + w * 16 + t * 8][0]);
        }
#pragma unroll
        for (int kk = 0; kk < 2; ++kk) {
            const int pc = ((kk * 4 + quad) ^ (r15 & 7)) * 8;
            bf16x8 af[MI], bfr[MJ];
#pragma unroll
            for (int i2 = 0; i2 < MI; ++i2)
                af[i2] = *(const bf16x8*)(&Alds[buf][wm + i2 * 16 + r15][pc]);
#pragma unroll
            for (int j = 0; j < MJ; ++j)
                bfr[j] = *(const bf16x8*)(&Blds[buf][wn + j * 16 + r15][pc]);
#pragma unroll
            for (int i2 = 0; i2 < MI; ++i2)
#pragma unroll
                for (int j = 0; j < MJ; ++j)
                    acc[i2][j] = __builtin_amdgcn_mfma_f32_16x16x32_bf16(
                        af[i2], bfr[j], acc[i2][j], 0, 0, 0);
        }
    }

    // C/D layout (verified m89/m91): col = lane&15, row = (lane>>4)*4 + reg
    const int row0 = bm + wm + quad * 4;
    const int col0 = bn + wn + r15;
    float* po = (MODE == 3 && SPLITK > 1 && z) ? outF2 : outF;
#pragma unroll
    for (int i = 0; i < MI; ++i) {
#pragma unroll
        for (int reg = 0; reg < 4; ++reg) {
            const int row = row0 + i * 16 + reg;
#pragma unroll
            for (int j = 0; j < MJ; ++j) {
                const int col = col0 + j * 16;
                float v = acc[i][j][reg];
                if (MODE == 0) {
                    outB[(size_t)row * N + col] = (bf16)v;
                } else if (MODE == 1) {
                    outF[(size_t)row * N + col] = v + bias[col] + res[(size_t)row * N + col];
                } else if (MODE == 2) {
                    v += bias[col];
                    outB[(size_t)row * N + col] = (bf16)fmaxf(v, 0.f);
                } else {
                    po[(size_t)row * N + col] = v;
                }
            }
        }
    }
}

// ---------------------------------------------------------------------------
// MFMA flash attention (causal), fixed-offset softmax (no online max):
//   p = exp2(S * 0.125*log2e - 28.854)  -> O,l accumulate LINEARLY.
// Async dbuf K/V staging via global_load_lds into XOR-swizzled unpadded
// [64][64] tiles. XCD head-grouping: 2 heads per XCD -> K/V L2-resident.
// Block = 4 waves; balanced q-tile pair {i, 31-i}; grid (16, H).
// ---------------------------------------------------------------------------
__global__ __launch_bounds__(256) void attn_kernel(
    const bf16* __restrict__ qkv, const bf16* __restrict__ vt,
    bf16* __restrict__ out)
{
    __shared__ __align__(16) bf16 Qs[64][64];
    __shared__ __align__(16) bf16 Ks[2][64][64];
    __shared__ __align__(16) bf16 Vs[2][64][64];
    __shared__ __align__(16) bf16 Ps[4][16][72];

    const int tid  = threadIdx.x;
    const int w    = tid >> 6;
    const int lane = tid & 63;
    const int r15  = lane & 15;
    const int quad = lane >> 4;
    const int rl   = lane >> 3;                   // 0..7 row in 8-row group
    const int gsw  = (lane & 7) ^ (rl & 7);       // swizzled global chunk

    // XCD head-grouping swizzle: 2 heads per XCD (K/V ~1 MB L2-resident)
    const int id  = blockIdx.x + 16 * blockIdx.y;
    const int seq = id >> 3;
    const int h   = (id & 7) * 2 + (seq & 1);
    const int qp  = seq >> 1;                     // 0..15 (q-tile pair)

    const bf16* qsec = qkv + h * 64;
    const bf16* ksec = qkv + 1024 + h * 64;
    const bf16* vth  = vt + (size_t)h * 64 * 2048;

#pragma unroll 1
    for (int half = 0; half < 2; ++half) {
        const int qt    = (half == 0) ? qp : 31 - qp;
        const int qrow0 = qt * 64;

        // stage Q (swizzled, g2l) + prefetch K/V step 0 into buf 0
#pragma unroll
        for (int t = 0; t < 2; ++t) {
            const int r = t * 32 + w * 8 + rl;
            ld_g2l(qsec + (size_t)(qrow0 + r) * 3072 + gsw * 8, &Qs[t * 32 + w * 8][0]);
            ld_g2l(ksec + (size_t)r * 3072 + gsw * 8, &Ks[0][t * 32 + w * 8][0]);
            ld_g2l(vth + (size_t)r * 2048 + gsw * 8, &Vs[0][t * 32 + w * 8][0]);
        }
        __syncthreads();   // all staging landed

        bf16x8 qf[2];
#pragma unroll
        for (int c = 0; c < 2; ++c) {
            const int p = ((c * 4 + quad) ^ (r15 & 7)) * 8;
            qf[c] = *(const bf16x8*)&Qs[w * 16 + r15][p];
        }

        float lacc[4] = {0.f, 0.f, 0.f, 0.f};
        floatx4 O[4];
#pragma unroll
        for (int j = 0; j < 4; ++j) O[j] = (floatx4)(0.f);

#pragma unroll 1
        for (int sb = 0; sb <= qt; ++sb) {
            const int buf = sb & 1;
            if (sb < qt) {   // prefetch next K/V into buf^1
                const int s1 = (sb + 1) * 64;
#pragma unroll
                for (int t = 0; t < 2; ++t) {
                    const int r = t * 32 + w * 8 + rl;
                    ld_g2l(ksec + (size_t)(s1 + r) * 3072 + gsw * 8, &Ks[buf ^ 1][t * 32 + w * 8][0]);
                    ld_g2l(vth + (size_t)r * 2048 + s1 + gsw * 8, &Vs[buf ^ 1][t * 32 + w * 8][0]);
                }
            }

            // S = Q K^T  (wave's 16 rows x 64 keys)
            floatx4 S[4];
#pragma unroll
            for (int j = 0; j < 4; ++j) S[j] = (floatx4)(0.f);
#pragma unroll
            for (int c = 0; c < 2; ++c) {
#pragma unroll
                for (int j = 0; j < 4; ++j) {
                    const int p = ((c * 4 + quad) ^ (r15 & 7)) * 8;
                    const bf16x8 b = *(const bf16x8*)&Ks[buf][j * 16 + r15][p];
                    S[j] = __builtin_amdgcn_mfma_f32_16x16x32_bf16(qf[c], b, S[j], 0, 0, 0);
                }
            }
            // fixed-offset softmax: p = exp2(S*0.125*log2e - 28.854)
            const bool diag = (sb == qt);
            const int rowl = w * 16 + quad * 4;
#pragma unroll
            for (int j = 0; j < 4; ++j) {
                const int col = j * 16 + r15;
#pragma unroll
                for (int r = 0; r < 4; ++r) {
                    float p = exp2f(fmaf(S[j][r], 0.18033688f, -28.853901f));
                    if (diag && col > rowl + r) p = 0.f;
                    S[j][r] = p;
                    lacc[r] += p;
                }
            }
            // P: C-layout -> A-layout via LDS (per-wave region, no barrier)
#pragma unroll
            for (int r = 0; r < 4; ++r)
#pragma unroll
                for (int j = 0; j < 4; ++j)
                    Ps[w][quad * 4 + r][j * 16 + r15] = (bf16)S[j][r];
            // O += P V
#pragma unroll
            for (int c = 0; c < 2; ++c) {
                const bf16x8 a = *(const bf16x8*)&Ps[w][r15][c * 32 + quad * 8];
#pragma unroll
                for (int j = 0; j < 4; ++j) {
                    const int p = ((c * 4 + quad) ^ (r15 & 7)) * 8;
                    const bf16x8 b = *(const bf16x8*)&Vs[buf][j * 16 + r15][p];
                    O[j] = __builtin_amdgcn_mfma_f32_16x16x32_bf16(a, b, O[j], 0, 0, 0);
                }
            }
            __syncthreads();  // drain prefetch (vmcnt) + protect buf reuse
        }
        // reduce l across the 16-lane row group (once per tile)
#pragma unroll
        for (int r = 0; r < 4; ++r) {
#pragma unroll
            for (int d = 1; d < 16; d <<= 1) lacc[r] += __shfl_xor(lacc[r], d);
        }
        // epilogue: out[q][h*64+dim] = O / l
#pragma unroll
        for (int r = 0; r < 4; ++r) {
            const float inv = 1.0f / lacc[r];
            const int row = qrow0 + w * 16 + quad * 4 + r;
#pragma unroll
            for (int j = 0; j < 4; ++j)
                out[(size_t)row * 1024 + h * 64 + j * 16 + r15] = (bf16)(O[j][r] * inv);
        }
    }
}

// ---------------------------------------------------------------------------
extern "C" void kernel_launch(void* const* d_in, const int* in_sizes, int n_in,
                              void* d_out, int out_size, void* d_ws, size_t ws_size,
                              hipStream_t stream)
{
    const float* x    = (const float*)d_in[0];
    const float* Wq   = (const float*)d_in[1];
    const float* Wk   = (const float*)d_in[2];
    const float* Wv   = (const float*)d_in[3];
    const float* Wo   = (const float*)d_in[4];
    const float* bo   = (const float*)d_in[5];
    const float* W1   = (const float*)d_in[6];
    const float* b1   = (const float*)d_in[7];
    const float* W2   = (const float*)d_in[8];
    const float* b2   = (const float*)d_in[9];
    const float* ln1s = (const float*)d_in[10];
    const float* ln1b = (const float*)d_in[11];
    const float* ln2s = (const float*)d_in[12];
    const float* ln2b = (const float*)d_in[13];

    char* ws = (char*)d_ws;
    bf16*  W1t  = (bf16*)(ws + 0);          //  8 MB (dead after FF1)
    bf16*  W2t  = (bf16*)(ws + 8388608);    //  8 MB
    bf16*  Obuf = (bf16*)(ws + 16777216);   //  4 MB
    float* x1   = (float*)(ws + 20971520);  //  8 MB
    bf16*  h2   = (bf16*)(ws + 29360128);   //  4 MB
    char*  rb    = ws + 33554432;
    bf16*  Wqkvt = (bf16*)(rb + 0);          //  6 MB
    bf16*  Wot   = (bf16*)(rb + 6291456);    //  2 MB
    bf16*  hbuf  = (bf16*)(rb + 8388608);    //  4 MB
    bf16*  QKV   = (bf16*)(rb + 12582912);   // 12 MB
    bf16*  Vt    = (bf16*)(rb + 25165824);   //  4 MB
    bf16*  ff1   = (bf16*)(rb + 0);          // 16 MB (aliases early region)
    float* psumA = (float*)(ws + 0);         //  8 MB over W1t (dead at FF2)
    float* psumB = (float*)(rb + 16777216);  //  8 MB over QKV tail (dead at FF2)

    const dim3 tb(32, 8);
    transpose_cast_kernel<<<dim3(2, 32, 16), tb, 0, stream>>>(Wq, Wqkvt,              1024, 64,   65536, 65536);
    transpose_cast_kernel<<<dim3(2, 32, 16), tb, 0, stream>>>(Wk, Wqkvt + 1024*1024,  1024, 64,   65536, 65536);
    transpose_cast_kernel<<<dim3(2, 32, 16), tb, 0, stream>>>(Wv, Wqkvt + 2048*1024,  1024, 64,   65536, 65536);
    transpose_cast_kernel<<<dim3(32, 32, 1), tb, 0, stream>>>(Wo, Wot, 1024, 1024, 0, 0);
    transpose_cast_kernel<<<dim3(128, 32, 1), tb, 0, stream>>>(W1, W1t, 1024, 4096, 0, 0);
    transpose_cast_kernel<<<dim3(32, 128, 1), tb, 0, stream>>>(W2, W2t, 4096, 1024, 0, 0);

    ln_kernel<<<2048, 256, 0, stream>>>(x, ln1s, ln1b, hbuf);
    // QKV: 64x128 tiles, 768 blocks; XCD swizzle 4 bn-grp x 2 bm-grp
    gemm_kernel<0,64,128,2,4,2,1,4,2><<<dim3(24, 32), 256, 0, stream>>>(hbuf, Wqkvt, 3072, 1024, nullptr, nullptr, QKV, nullptr, nullptr);
    transpose_head_kernel<<<dim3(2, 64, 16), tb, 0, stream>>>(QKV, Vt, 2048);
    attn_kernel<<<dim3(16, 16), 256, 0, stream>>>(QKV, Vt, Obuf);
    // Oproj: 64x64 tiles, 512 blocks
    gemm_kernel<1,64,64,2,2,2,1,4,2><<<dim3(16, 32), 256, 0, stream>>>(Obuf, Wot, 1024, 1024, x1, nullptr, nullptr, bo, x);
    ln_kernel<<<2048, 256, 0, stream>>>(x1, ln2s, ln2b, h2);
    // FF1: 64x128 tiles, 1024 blocks
    gemm_kernel<2,64,128,2,4,2,1,4,2><<<dim3(32, 32), 256, 0, stream>>>(h2, W1t, 4096, 1024, nullptr, nullptr, ff1, b1, nullptr);
    // FF2: 64x128 tiles, split-K=2, 512 blocks; XCD swizzle 2 bn-grp x 4 bm-grp
    gemm_kernel<3,64,128,2,4,2,2,2,4><<<dim3(8, 32, 2), 256, 0, stream>>>(ff1, W2t, 1024, 4096, psumA, psumB, nullptr, nullptr, nullptr);
    reduce_kernel<<<2048, 256, 0, stream>>>(psumA, psumB, b2, x1, (float*)d_out);
}